// Round 8
// baseline (250.719 us; speedup 1.0000x reference)
//
#include <hip/hip_runtime.h>
#include <hip/hip_bf16.h>
#include <cstdint>
#include <cstddef>

// Problem constants
#define BB 4
#define SS 1024
#define DD 1024
#define HH 16
#define DKK 64

typedef unsigned short u16;
typedef __bf16 bf16_t;
typedef __attribute__((ext_vector_type(8))) bf16_t bf16x8;
typedef __attribute__((ext_vector_type(4))) float floatx4;

#define LOG2E 1.4426950408889634f
#define QKSCALE 0.18033688011112042f   // 0.125 * log2(e)

// fp32 -> bf16 round-to-nearest-even
static __device__ inline u16 f2bf(float f) {
    union { float f; unsigned u; } v; v.f = f;
    unsigned r = v.u + 0x7fffu + ((v.u >> 16) & 1u);
    return (u16)(r >> 16);
}

// async global->LDS, 16B per lane. LDS dest must be wave-uniform base; HW adds lane*16.
static __device__ inline void load16_lds(const void* g, void* l) {
    __builtin_amdgcn_global_load_lds(
        (const __attribute__((address_space(1))) unsigned int*)g,
        (__attribute__((address_space(3))) unsigned int*)l,
        16, 0, 0);
}

// XOR-swizzled LDS u16 index for (row, 16B-chunk) tiles, 8 chunks/row (64 u16).
static __device__ inline int swz64(int row, int c) { return row * 64 + ((c ^ (row & 7)) * 8); }

static __device__ inline float lam_val(const int* p) {
    int v = *p;
    if (v >= -100000 && v <= 100000) return (float)v;   // stored as int32
    union { int i; float f; } u; u.i = v; return u.f;    // hedge: stored as fp32 bits
}

// ---------------------------------------------------------------------------
// 1) prep: blocks 0..1023 = bias transpose + maskOut; blocks 1024..5119 =
//    fp32->bf16 conversion, 2x(float4 pair) per thread with 16B stores.
//    Bias is written in attn fragment-order layout biasT[b][kt][j][quad][q][4]
//    (values prescaled by log2e) so attn's per-lane uint2 bias loads are
//    fully coalesced.
// ---------------------------------------------------------------------------
__global__ void prep_kernel(const float* __restrict__ Qx, const float* __restrict__ Kx,
                            const float* __restrict__ Vx,
                            const float* __restrict__ Wq, const float* __restrict__ Wk,
                            const float* __restrict__ Wv, const float* __restrict__ Wo,
                            const float* __restrict__ prob, const int* __restrict__ mask,
                            const int* __restrict__ lam_p,
                            u16* __restrict__ Xq, u16* __restrict__ Xk, u16* __restrict__ Xv,
                            u16* __restrict__ wq, u16* __restrict__ wk,
                            u16* __restrict__ wv, u16* __restrict__ wo,
                            u16* __restrict__ biasT, float* __restrict__ maskOut)
{
    __shared__ float tile[64][65];
    __shared__ u16 btile[64][68];   // [q_local][k_local] bf16 bias values
    const int blk = blockIdx.x, tid = threadIdx.x;

    if (blk >= 1024) {
        const int cb = blk - 1024;
        const int base = cb * 1024;            // float4 units
        const float* src; u16* dst; int off0;
        if (base < 3145728) {
            int s = base >> 20;  off0 = base & 1048575;
            src = (s == 0) ? Qx : (s == 1) ? Kx : Vx;
            dst = (s == 0) ? Xq : (s == 1) ? Xk : Xv;
        } else {
            int v2 = base - 3145728;
            int s = v2 >> 18;  off0 = v2 & 262143;
            src = (s == 0) ? Wq : (s == 1) ? Wk : (s == 2) ? Wv : Wo;
            dst = (s == 0) ? wq : (s == 1) ? wk : (s == 2) ? wv : wo;
        }
        const float4* s4 = (const float4*)src;
        #pragma unroll
        for (int r = 0; r < 2; ++r) {
            int i4 = off0 + r * 512 + tid * 2;   // pair of consecutive float4
            float4 a  = s4[i4];
            float4 b2 = s4[i4 + 1];
            uint4 pk;
            pk.x = (unsigned)f2bf(a.x)  | ((unsigned)f2bf(a.y)  << 16);
            pk.y = (unsigned)f2bf(a.z)  | ((unsigned)f2bf(a.w)  << 16);
            pk.z = (unsigned)f2bf(b2.x) | ((unsigned)f2bf(b2.y) << 16);
            pk.w = (unsigned)f2bf(b2.z) | ((unsigned)f2bf(b2.w) << 16);
            *(uint4*)((ushort4*)dst + i4) = pk;   // 16B coalesced store
        }
        return;
    }

    // bias branch: 1024 blocks, 64x64 tile (q-tile q0, k-tile k0 = kt*64)
    const int b = blk >> 8;
    const int q0 = ((blk >> 4) & 15) * 64, k0 = (blk & 15) * 64;
    const int kt = blk & 15;
    #pragma unroll
    for (int rr = 0; rr < 4; ++rr) {
        int unit = rr * 256 + tid;
        int kl = unit >> 4, qi = unit & 15;
        float4 p4 = *(const float4*)&prob[((size_t)(b * SS + k0 + kl)) * SS + q0 + qi * 4];
        tile[kl][qi * 4 + 0] = p4.x;
        tile[kl][qi * 4 + 1] = p4.y;
        tile[kl][qi * 4 + 2] = p4.z;
        tile[kl][qi * 4 + 3] = p4.w;
    }
    __syncthreads();
    const float lamc = lam_val(lam_p) * LOG2E;
    #pragma unroll
    for (int rr = 0; rr < 4; ++rr) {
        int pair = rr * 256 + tid;
        int q = pair >> 4, k4 = pair & 15;
        size_t midx = ((size_t)(b * SS + q0 + q)) * SS + k0 + k4 * 4;
        int4 m4 = *(const int4*)&mask[midx];
        float p0 = tile[k4 * 4 + 0][q];
        float p1 = tile[k4 * 4 + 1][q];
        float p2 = tile[k4 * 4 + 2][q];
        float p3 = tile[k4 * 4 + 3][q];
        ushort4 bb;
        bb.x = f2bf((m4.x == 0) ? -1.5e9f : -lamc * p0);
        bb.y = f2bf((m4.y == 0) ? -1.5e9f : -lamc * p1);
        bb.z = f2bf((m4.z == 0) ? -1.5e9f : -lamc * p2);
        bb.w = f2bf((m4.w == 0) ? -1.5e9f : -lamc * p3);
        *(ushort4*)&btile[q][k4 * 4] = bb;
        if (maskOut) {
            float4 mf = { (float)m4.x, (float)m4.y, (float)m4.z, (float)m4.w };
            *(float4*)&maskOut[midx] = mf;
        }
    }
    __syncthreads();
    // coalesced biasT write: [b][kt][j][quad][q(1024 global)][4] u16
    u16* bT = biasT + (size_t)(b * 16 + kt) * 65536;
    #pragma unroll
    for (int rr = 0; rr < 4; ++rr) {
        int idx = rr * 256 + tid;                 // (j, quad, q_local)
        int j = idx >> 8, quad = (idx >> 6) & 3, ql = idx & 63;
        ushort4 v = *(const ushort4*)&btile[ql][j * 16 + quad * 4];
        *(ushort4*)&bT[(size_t)((j * 4 + quad) * 1024 + q0 + ql) * 4] = v;
    }
}

// ---------------------------------------------------------------------------
// 2) GEMM: 128x128 tile, BK=64, T3 2-phase double-buffer with STATIC buffer
//    names (As0/Bs0 vs As1/Bs1).  Round-7 diagnosis: occupancy is register-
//    capped at 2 blocks/CU (VGPR 100 + 64 acc-AGPR = 164 > 128 threshold),
//    so 64KB LDS for the second buffer is free.  Static arrays (not
//    buf[cur]) keep alias analysis exact so the compiler does NOT insert an
//    early vmcnt(0) drain before the ds_reads (round-2 lesson).  Per K-step:
//    STAGE(next tile -> other buf), compute current buf, ONE barrier (its
//    conservative vmcnt drain completes the prefetch, which had the whole
//    compute phase to land).
// ---------------------------------------------------------------------------
template <int MODE>
static __device__ inline void gemm_body(const u16* __restrict__ A, const u16* __restrict__ W,
                                        const float* __restrict__ bias,
                                        u16* __restrict__ Cb, float* __restrict__ Cf,
                                        int mBase, int nBase,
                                        u16* As0, u16* Bs0, u16* As1, u16* Bs1)
{
    constexpr int K = 1024, N = 1024;
    const int tid = threadIdx.x;
    const int wv = tid >> 6, ln = tid & 63, l15 = ln & 15, quad = ln >> 4;
    const int wm = (wv & 1) * 64, wn = (wv >> 1) * 64;

    // 128x64-u16 staging map: 1024 units of 16B, 8 chunks/row, 4 rounds/wave
    const u16* Aptr[4]; const u16* Wptr[4];
    #pragma unroll
    for (int r = 0; r < 4; ++r) {
        int p = r * 256 + wv * 64 + ln;     // 0..1023
        int row = p >> 3;                   // 0..127
        int c = (p & 7) ^ (row & 7);
        Aptr[r] = A + (size_t)(mBase + row) * K + c * 8;
        Wptr[r] = W + (size_t)(nBase + row) * K + c * 8;
    }

    floatx4 acc[4][4] = {};

#define G_STAGE(k0, Ad, Bd)                                              \
    {                                                                    \
        _Pragma("unroll")                                                \
        for (int r = 0; r < 4; ++r) {                                    \
            load16_lds(Aptr[r] + (k0), &Ad[(r * 256 + wv * 64) * 8]);    \
            load16_lds(Wptr[r] + (k0), &Bd[(r * 256 + wv * 64) * 8]);    \
        }                                                                \
    }

#define G_COMPUTE(Asrc, Bsrc)                                            \
    {                                                                    \
        _Pragma("unroll")                                                \
        for (int t = 0; t < 2; ++t) {                                    \
            bf16x8 af[4], bfr[4];                                        \
            _Pragma("unroll")                                            \
            for (int i = 0; i < 4; ++i)                                  \
                af[i] = *(const bf16x8*)&Asrc[swz64(wm + i * 16 + l15, t * 4 + quad)]; \
            _Pragma("unroll")                                            \
            for (int j = 0; j < 4; ++j)                                  \
                bfr[j] = *(const bf16x8*)&Bsrc[swz64(wn + j * 16 + l15, t * 4 + quad)]; \
            _Pragma("unroll")                                            \
            for (int i = 0; i < 4; ++i)                                  \
                _Pragma("unroll")                                        \
                for (int j = 0; j < 4; ++j)                              \
                    acc[i][j] = __builtin_amdgcn_mfma_f32_16x16x32_bf16(af[i], bfr[j], acc[i][j], 0, 0, 0); \
        }                                                                \
    }

    // prologue: stage k=0 into buf0; drain
    G_STAGE(0, As0, Bs0);
    __syncthreads();

    // 2-phase pipeline, unrolled by 2 K-steps (static buffer names)
    for (int k0 = 0; k0 < K; k0 += 128) {
        if (k0 + 64 < K) G_STAGE(k0 + 64, As1, Bs1);
        G_COMPUTE(As0, Bs0);
        __syncthreads();            // prefetch landed + buf0 reads done
        if (k0 + 128 < K) G_STAGE(k0 + 128, As0, Bs0);
        G_COMPUTE(As1, Bs1);
        __syncthreads();            // prefetch landed + buf1 reads done
    }
#undef G_STAGE
#undef G_COMPUTE

    #pragma unroll
    for (int i = 0; i < 4; ++i) {
        #pragma unroll
        for (int j = 0; j < 4; ++j) {
            int col = nBase + wn + j * 16 + l15;
            float bcol = bias[col];
            if (MODE == 2) {
                int hh = col >> 6, dk = col & 63;
                int row0 = mBase + wm + i * 16 + quad * 4;
                int bb = row0 >> 10, s = row0 & 1023;
                ushort4 v4;
                v4.x = f2bf(acc[i][j][0] + bcol);
                v4.y = f2bf(acc[i][j][1] + bcol);
                v4.z = f2bf(acc[i][j][2] + bcol);
                v4.w = f2bf(acc[i][j][3] + bcol);
                *(ushort4*)&Cb[((size_t)((bb * HH + hh) * DKK) + dk) * SS + s] = v4;
            } else {
                #pragma unroll
                for (int r = 0; r < 4; ++r) {
                    int row = mBase + wm + i * 16 + quad * 4 + r;
                    float v = acc[i][j][r] + bcol;
                    if (MODE == 1) Cf[(size_t)row * N + col] = v;
                    else           Cb[(size_t)row * N + col] = f2bf(v);
                }
            }
        }
    }
}

__global__ __launch_bounds__(256) void gemm_qkv_kernel(
    const u16* __restrict__ Xq, const u16* __restrict__ Xk, const u16* __restrict__ Xv,
    const u16* __restrict__ Wq, const u16* __restrict__ Wk, const u16* __restrict__ Wv,
    const float* __restrict__ bq, const float* __restrict__ bk, const float* __restrict__ bv,
    u16* __restrict__ Cq, u16* __restrict__ Ck, u16* __restrict__ Vtout)
{
    __shared__ __align__(16) u16 As0[128 * 64];
    __shared__ __align__(16) u16 Bs0[128 * 64];
    __shared__ __align__(16) u16 As1[128 * 64];
    __shared__ __align__(16) u16 Bs1[128 * 64];

    // T1 bijective XCD swizzle: 768 blocks (768%8==0), chunk = 96.
    const int lin = blockIdx.x + 8 * blockIdx.y + 256 * blockIdx.z;   // 0..767
    const int sw  = (lin & 7) * 96 + (lin >> 3);
    const int x = sw & 7, y = (sw >> 3) & 31, z = sw >> 8;
    const int mBase = y * 128, nBase = x * 128;

    if (z == 2) {
        gemm_body<2>(Xv, Wv, bv, Vtout, nullptr, mBase, nBase, As0, Bs0, As1, Bs1);
    } else {
        const u16* A = (z == 0) ? Xq : Xk;
        const u16* W = (z == 0) ? Wq : Wk;
        const float* bias = (z == 0) ? bq : bk;
        u16* C = (z == 0) ? Cq : Ck;
        gemm_body<0>(A, W, bias, C, nullptr, mBase, nBase, As0, Bs0, As1, Bs1);
    }
}

__global__ __launch_bounds__(256) void gemm_out_kernel(
    const u16* __restrict__ A, const u16* __restrict__ W,
    const float* __restrict__ bias, float* __restrict__ Cf)
{
    __shared__ __align__(16) u16 As0[128 * 64];
    __shared__ __align__(16) u16 Bs0[128 * 64];
    __shared__ __align__(16) u16 As1[128 * 64];
    __shared__ __align__(16) u16 Bs1[128 * 64];

    // 256 blocks, chunk = 32
    const int lin = blockIdx.x + 8 * blockIdx.y;                      // 0..255
    const int sw  = (lin & 7) * 32 + (lin >> 3);
    const int x = sw & 7, y = sw >> 3;
    gemm_body<1>(A, W, bias, nullptr, Cf, y * 128, x * 128, As0, Bs0, As1, Bs1);
}

// ---------------------------------------------------------------------------
// 3) Flash attention, QT=64, transposed-S variant (unchanged from round 5:
//    single-buffer K/V LDS staging + XCD swizzle + fragment-order bias +
//    operand-swapped PV giving lane-local rsum and ushort4 epilogue).
// ---------------------------------------------------------------------------
__global__ __launch_bounds__(256) void attn_kernel(
    const u16* __restrict__ Qf, const u16* __restrict__ Kf,
    const u16* __restrict__ Vt, const u16* __restrict__ biasT,
    u16* __restrict__ Attn)
{
    __shared__ __align__(16) u16 Qs[64 * 64];
    __shared__ __align__(16) u16 Ks[64 * 64];
    __shared__ __align__(16) u16 Vs[64 * 64];      // [dk][ks] swizzled
    __shared__ __align__(16) u16 Ps[4][16 * 72];   // per-wave [q][k], +8 pad
    const int tid = threadIdx.x;
    const int wv = tid >> 6, ln = tid & 63, l15 = ln & 15, quad = ln >> 4;

    // T1: bijective XCD swizzle (1024 blocks, 1024%8==0).
    const int lin = blockIdx.x + 16 * blockIdx.y + 256 * blockIdx.z;  // 0..1023
    const int sw  = (lin & 7) * 128 + (lin >> 3);
    const int qt = sw & 15, h = (sw >> 4) & 15, b = sw >> 8;
    const int q0 = qt * 64;

    // 64x64-u16 staging map (8 chunks/row)
    int row64[2], col64[2];
    #pragma unroll
    for (int r = 0; r < 2; ++r) {
        int p = r * 256 + wv * 64 + ln;
        row64[r] = p >> 3;
        col64[r] = ((p & 7) ^ (row64[r] & 7)) * 8;
    }

    // stage Q tile [64 q][64 dk]
    #pragma unroll
    for (int r = 0; r < 2; ++r)
        load16_lds(Qf + ((size_t)(b * SS + q0 + row64[r])) * DD + h * DKK + col64[r],
                   &Qs[(r * 256 + wv * 64) * 8]);
    __syncthreads();

    // loop-invariant Q fragments (B-operand in QK^T)
    bf16x8 aq[2];
    #pragma unroll
    for (int t = 0; t < 2; ++t)
        aq[t] = *(const bf16x8*)&Qs[swz64(wv * 16 + l15, t * 4 + quad)];

    const size_t vt_head = ((size_t)(b * HH + h)) * DKK * SS;
    const u16* Kp[2]; const u16* Vp[2];
    #pragma unroll
    for (int r = 0; r < 2; ++r) {
        Kp[r] = Kf + ((size_t)(b * SS + row64[r])) * DD + h * DKK + col64[r];
        Vp[r] = Vt + vt_head + (size_t)row64[r] * SS + col64[r];
    }

    // bias: fragment-order layout [b][kt][j][quad][q][4]; per-lane base
    const int qq = q0 + wv * 16 + l15;
    const u16* bpT = biasT + (size_t)b * 1048576 + (size_t)quad * 4096 + (size_t)qq * 4;

    floatx4 o[4] = {};
    float rsum = 0.f;

    for (int kt = 0; kt < 16; ++kt) {
        const int kk0 = kt * 64;
        __syncthreads();    // prior-iteration K/V LDS reads complete
        #pragma unroll
        for (int r = 0; r < 2; ++r) {
            load16_lds(Kp[r] + (size_t)kk0 * DD, &Ks[(r * 256 + wv * 64) * 8]);
            load16_lds(Vp[r] + kk0, &Vs[(r * 256 + wv * 64) * 8]);
        }
        __syncthreads();    // staging complete

        // bias loads: 4 coalesced uint2, latency hides under QK MFMAs
        uint2 braw[4];
        #pragma unroll
        for (int j = 0; j < 4; ++j)
            braw[j] = *(const uint2*)&bpT[(size_t)kt * 65536 + j * 16384];

        // S^T = K Q^T : row = k-within-16 (quad*4+r), col = q (l15)
        floatx4 sfr[4];
        #pragma unroll
        for (int j = 0; j < 4; ++j) {
            bf16x8 bk0 = *(const bf16x8*)&Ks[swz64(j * 16 + l15, quad)];
            bf16x8 bk1 = *(const bf16x8*)&Ks[swz64(j * 16 + l15, 4 + quad)];
            floatx4 s = {};
            s = __builtin_amdgcn_mfma_f32_16x16x32_bf16(bk0, aq[0], s, 0, 0, 0);
            sfr[j] = __builtin_amdgcn_mfma_f32_16x16x32_bf16(bk1, aq[1], s, 0, 0, 0);
        }

        // softmax: p = exp2(s*0.1803.. + bias2); packed b64 P-stores
        #pragma unroll
        for (int j = 0; j < 4; ++j) {
            float b0 = __uint_as_float(braw[j].x << 16);
            float b1 = __uint_as_float(braw[j].x & 0xffff0000u);
            float b2 = __uint_as_float(braw[j].y << 16);
            float b3 = __uint_as_float(braw[j].y & 0xffff0000u);
            float p0 = __builtin_amdgcn_exp2f(fmaf(sfr[j][0], QKSCALE, b0));
            float p1 = __builtin_amdgcn_exp2f(fmaf(sfr[j][1], QKSCALE, b1));
            float p2 = __builtin_amdgcn_exp2f(fmaf(sfr[j][2], QKSCALE, b2));
            float p3 = __builtin_amdgcn_exp2f(fmaf(sfr[j][3], QKSCALE, b3));
            rsum += (p0 + p1) + (p2 + p3);
            uint2 pk;
            pk.x = (__float_as_uint(p0) >> 16) | (__float_as_uint(p1) & 0xffff0000u);
            pk.y = (__float_as_uint(p2) >> 16) | (__float_as_uint(p3) & 0xffff0000u);
            *(uint2*)&Ps[wv][l15 * 72 + j * 16 + quad * 4] = pk;
        }

        // O^T += V^T P^T  (operand-swapped: A=V-frag, B=P-frag; Ps wave-private)
        #pragma unroll
        for (int t = 0; t < 2; ++t) {
            bf16x8 ap = *(const bf16x8*)&Ps[wv][l15 * 72 + t * 32 + quad * 8];
            #pragma unroll
            for (int j = 0; j < 4; ++j) {
                bf16x8 bvv = *(const bf16x8*)&Vs[swz64(j * 16 + l15, t * 4 + quad)];
                o[j] = __builtin_amdgcn_mfma_f32_16x16x32_bf16(bvv, ap, o[j], 0, 0, 0);
            }
        }
    }

    // rsum: butterfly over quads (bits 4,5) -> every lane holds the full
    // row-sum for its own q = l15.  No LDS bounce needed.
    rsum += __shfl_xor(rsum, 16);
    rsum += __shfl_xor(rsum, 32);
    const float ri = 1.0f / rsum;

    // epilogue: o[j][r] = O[q=qq][dk = j*16 + quad*4 + r] -> 4 ushort4 stores
    u16* outp = Attn + ((size_t)(b * SS + qq)) * DD + h * DKK + quad * 4;
    #pragma unroll
    for (int j = 0; j < 4; ++j) {
        ushort4 v4;
        v4.x = f2bf(o[j][0] * ri);
        v4.y = f2bf(o[j][1] * ri);
        v4.z = f2bf(o[j][2] * ri);
        v4.w = f2bf(o[j][3] * ri);
        *(ushort4*)&outp[j * 16] = v4;
    }
}

// ---------------------------------------------------------------------------
// launch
// ---------------------------------------------------------------------------
extern "C" void kernel_launch(void* const* d_in, const int* in_sizes, int n_in,
                              void* d_out, int out_size, void* d_ws, size_t ws_size,
                              hipStream_t stream)
{
    const float* Qx  = (const float*)d_in[0];
    const float* Kx  = (const float*)d_in[1];
    const float* Vx  = (const float*)d_in[2];
    const float* prob = (const float*)d_in[3];
    const int*   mask = (const int*)d_in[4];
    const int*   lam  = (const int*)d_in[5];
    const float* Wq  = (const float*)d_in[6];
    const float* bq  = (const float*)d_in[7];
    const float* Wk  = (const float*)d_in[8];
    const float* bk  = (const float*)d_in[9];
    const float* Wv  = (const float*)d_in[10];
    const float* bv  = (const float*)d_in[11];
    const float* Wo  = (const float*)d_in[12];
    const float* bo  = (const float*)d_in[13];

    char* ws = (char*)d_ws;
    const size_t MB = 1024 * 1024;
    u16*   Xq     = (u16*)(ws + 0 * MB);
    u16*   Xk     = (u16*)(ws + 8 * MB);
    u16*   Xv     = (u16*)(ws + 16 * MB);
    u16*   wq     = (u16*)(ws + 24 * MB);
    u16*   wk     = (u16*)(ws + 26 * MB);
    u16*   wvp    = (u16*)(ws + 28 * MB);
    u16*   wo     = (u16*)(ws + 30 * MB);
    u16*   q_flat = (u16*)(ws + 32 * MB);
    u16*   k_flat = (u16*)(ws + 40 * MB);
    u16*   vt     = (u16*)(ws + 56 * MB);
    u16*   biasT  = (u16*)(ws + 64 * MB);   // 8MB bf16 [b][kt][j][quad][q][4], prescaled by log2e
    u16*   attn   = (u16*)(ws + 80 * MB);

    float* maskOut = (out_size >= 2 * BB * SS * DD) ? (float*)d_out + (size_t)BB * SS * DD
                                                    : nullptr;

    prep_kernel<<<5120, 256, 0, stream>>>(Qx, Kx, Vx, Wq, Wk, Wv, Wo, prob, mask, lam,
                                          Xq, Xk, Xv, wq, wk, wvp, wo, biasT, maskOut);
    gemm_qkv_kernel<<<dim3(8, 32, 3), 256, 0, stream>>>(Xq, Xk, Xv, wq, wk, wvp,
                                                        bq, bk, bv, q_flat, k_flat, vt);
    attn_kernel<<<dim3(16, 16, 4), 256, 0, stream>>>(q_flat, k_flat, vt, biasT, attn);
    gemm_out_kernel<<<dim3(8, 32, 1), 256, 0, stream>>>(attn, wo, bo, (float*)d_out);
}

// Round 9
// 248.490 us; speedup vs baseline: 1.0090x; 1.0090x over previous
//
#include <hip/hip_runtime.h>
#include <hip/hip_bf16.h>
#include <cstdint>
#include <cstddef>

// Problem constants
#define BB 4
#define SS 1024
#define DD 1024
#define HH 16
#define DKK 64

typedef unsigned short u16;
typedef __bf16 bf16_t;
typedef __attribute__((ext_vector_type(8))) bf16_t bf16x8;
typedef __attribute__((ext_vector_type(4))) float floatx4;

#define LOG2E 1.4426950408889634f
#define QKSCALE 0.18033688011112042f   // 0.125 * log2(e)

// fp32 -> bf16 round-to-nearest-even
static __device__ inline u16 f2bf(float f) {
    union { float f; unsigned u; } v; v.f = f;
    unsigned r = v.u + 0x7fffu + ((v.u >> 16) & 1u);
    return (u16)(r >> 16);
}

// async global->LDS, 16B per lane. LDS dest must be wave-uniform base; HW adds lane*16.
static __device__ inline void load16_lds(const void* g, void* l) {
    __builtin_amdgcn_global_load_lds(
        (const __attribute__((address_space(1))) unsigned int*)g,
        (__attribute__((address_space(3))) unsigned int*)l,
        16, 0, 0);
}

// XOR-swizzled LDS u16 index for (row, 16B-chunk) tiles, 8 chunks/row (64 u16).
static __device__ inline int swz64(int row, int c) { return row * 64 + ((c ^ (row & 7)) * 8); }

static __device__ inline float lam_val(const int* p) {
    int v = *p;
    if (v >= -100000 && v <= 100000) return (float)v;   // stored as int32
    union { int i; float f; } u; u.i = v; return u.f;    // hedge: stored as fp32 bits
}

// ---------------------------------------------------------------------------
// 1) prep: blocks 0..1023 = bias transpose + maskOut; blocks 1024..5119 =
//    fp32->bf16 conversion.  LDS shrunk to ONE 64x65-f32 tile (16.6 KB):
//    the bias bf16 values are held in registers across a barrier, then the
//    SAME LDS storage is reused (union) for the [q][k] u16 staging of the
//    fragment-order biasT write.  25.6 KB -> 16.6 KB lifts the whole-kernel
//    occupancy cap 6 -> 8 blocks/CU (prep was latency-bound: VALU 5%,
//    HBM 32%, occupancy 45%).
// ---------------------------------------------------------------------------
__global__ void prep_kernel(const float* __restrict__ Qx, const float* __restrict__ Kx,
                            const float* __restrict__ Vx,
                            const float* __restrict__ Wq, const float* __restrict__ Wk,
                            const float* __restrict__ Wv, const float* __restrict__ Wo,
                            const float* __restrict__ prob, const int* __restrict__ mask,
                            const int* __restrict__ lam_p,
                            u16* __restrict__ Xq, u16* __restrict__ Xk, u16* __restrict__ Xv,
                            u16* __restrict__ wq, u16* __restrict__ wk,
                            u16* __restrict__ wv, u16* __restrict__ wo,
                            u16* __restrict__ biasT, float* __restrict__ maskOut)
{
    __shared__ union {
        float tile[64][65];     // 16640 B
        u16   btile[64][68];    //  8704 B (reused after barrier)
    } sh;
    const int blk = blockIdx.x, tid = threadIdx.x;

    if (blk >= 1024) {
        const int cb = blk - 1024;
        const int base = cb * 1024;            // float4 units
        const float* src; u16* dst; int off0;
        if (base < 3145728) {
            int s = base >> 20;  off0 = base & 1048575;
            src = (s == 0) ? Qx : (s == 1) ? Kx : Vx;
            dst = (s == 0) ? Xq : (s == 1) ? Xk : Xv;
        } else {
            int v2 = base - 3145728;
            int s = v2 >> 18;  off0 = v2 & 262143;
            src = (s == 0) ? Wq : (s == 1) ? Wk : (s == 2) ? Wv : Wo;
            dst = (s == 0) ? wq : (s == 1) ? wk : (s == 2) ? wv : wo;
        }
        const float4* s4 = (const float4*)src;
        #pragma unroll
        for (int r = 0; r < 2; ++r) {
            int i4 = off0 + r * 512 + tid * 2;   // pair of consecutive float4
            float4 a  = s4[i4];
            float4 b2 = s4[i4 + 1];
            uint4 pk;
            pk.x = (unsigned)f2bf(a.x)  | ((unsigned)f2bf(a.y)  << 16);
            pk.y = (unsigned)f2bf(a.z)  | ((unsigned)f2bf(a.w)  << 16);
            pk.z = (unsigned)f2bf(b2.x) | ((unsigned)f2bf(b2.y) << 16);
            pk.w = (unsigned)f2bf(b2.z) | ((unsigned)f2bf(b2.w) << 16);
            *(uint4*)((ushort4*)dst + i4) = pk;   // 16B coalesced store
        }
        return;
    }

    // bias branch: 1024 blocks, 64x64 tile (q-tile q0, k-tile k0 = kt*64)
    const int b = blk >> 8;
    const int q0 = ((blk >> 4) & 15) * 64, k0 = (blk & 15) * 64;
    const int kt = blk & 15;
    #pragma unroll
    for (int rr = 0; rr < 4; ++rr) {
        int unit = rr * 256 + tid;
        int kl = unit >> 4, qi = unit & 15;
        float4 p4 = *(const float4*)&prob[((size_t)(b * SS + k0 + kl)) * SS + q0 + qi * 4];
        sh.tile[kl][qi * 4 + 0] = p4.x;
        sh.tile[kl][qi * 4 + 1] = p4.y;
        sh.tile[kl][qi * 4 + 2] = p4.z;
        sh.tile[kl][qi * 4 + 3] = p4.w;
    }
    __syncthreads();
    const float lamc = lam_val(lam_p) * LOG2E;
    ushort4 bbv[4];
    int qv[4], k4v[4];
    #pragma unroll
    for (int rr = 0; rr < 4; ++rr) {
        int pair = rr * 256 + tid;
        int q = pair >> 4, k4 = pair & 15;
        qv[rr] = q; k4v[rr] = k4;
        size_t midx = ((size_t)(b * SS + q0 + q)) * SS + k0 + k4 * 4;
        int4 m4 = *(const int4*)&mask[midx];
        float p0 = sh.tile[k4 * 4 + 0][q];
        float p1 = sh.tile[k4 * 4 + 1][q];
        float p2 = sh.tile[k4 * 4 + 2][q];
        float p3 = sh.tile[k4 * 4 + 3][q];
        bbv[rr].x = f2bf((m4.x == 0) ? -1.5e9f : -lamc * p0);
        bbv[rr].y = f2bf((m4.y == 0) ? -1.5e9f : -lamc * p1);
        bbv[rr].z = f2bf((m4.z == 0) ? -1.5e9f : -lamc * p2);
        bbv[rr].w = f2bf((m4.w == 0) ? -1.5e9f : -lamc * p3);
        if (maskOut) {
            float4 mf = { (float)m4.x, (float)m4.y, (float)m4.z, (float)m4.w };
            *(float4*)&maskOut[midx] = mf;
        }
    }
    __syncthreads();    // all tile reads complete; safe to reuse storage
    #pragma unroll
    for (int rr = 0; rr < 4; ++rr)
        *(ushort4*)&sh.btile[qv[rr]][k4v[rr] * 4] = bbv[rr];
    __syncthreads();
    // coalesced biasT write: [b][kt][j][quad][q(1024 global)][4] u16
    u16* bT = biasT + (size_t)(b * 16 + kt) * 65536;
    #pragma unroll
    for (int rr = 0; rr < 4; ++rr) {
        int idx = rr * 256 + tid;                 // (j, quad, q_local)
        int j = idx >> 8, quad = (idx >> 6) & 3, ql = idx & 63;
        ushort4 v = *(const ushort4*)&sh.btile[ql][j * 16 + quad * 4];
        *(ushort4*)&bT[(size_t)((j * 4 + quad) * 1024 + q0 + ql) * 4] = v;
    }
}

// ---------------------------------------------------------------------------
// 2) GEMM: round-7 body (measured best 43.2 us): 128x128 tile, BK=64,
//    single-buffer, kernel-scope shared (32 KB), serial stage/drain.
//    Round-8 lesson: dbuf added +16 VGPR, crossing the 512/3=170.7 unified
//    reg boundary (164 -> 180) => 3 -> 2 waves/SIMD, -24% perf.  Keep the
//    register footprint AT 100 VGPR + 64 acc = 164.
// ---------------------------------------------------------------------------
template <int MODE>
static __device__ inline void gemm_body(const u16* __restrict__ A, const u16* __restrict__ W,
                                        const float* __restrict__ bias,
                                        u16* __restrict__ Cb, float* __restrict__ Cf,
                                        int mBase, int nBase,
                                        u16* As, u16* Bs)
{
    constexpr int K = 1024, N = 1024;
    const int tid = threadIdx.x;
    const int wv = tid >> 6, ln = tid & 63, l15 = ln & 15, quad = ln >> 4;
    const int wm = (wv & 1) * 64, wn = (wv >> 1) * 64;

    // 128x64-u16 staging map: 1024 units of 16B, 8 chunks/row, 4 rounds/wave
    const u16* Aptr[4]; const u16* Wptr[4];
    #pragma unroll
    for (int r = 0; r < 4; ++r) {
        int p = r * 256 + wv * 64 + ln;     // 0..1023
        int row = p >> 3;                   // 0..127
        int c = (p & 7) ^ (row & 7);
        Aptr[r] = A + (size_t)(mBase + row) * K + c * 8;
        Wptr[r] = W + (size_t)(nBase + row) * K + c * 8;
    }

    floatx4 acc[4][4] = {};

    for (int k0 = 0; k0 < K; k0 += 64) {
        __syncthreads();
        #pragma unroll
        for (int r = 0; r < 4; ++r) {
            load16_lds(Aptr[r] + k0, &As[(r * 256 + wv * 64) * 8]);
            load16_lds(Wptr[r] + k0, &Bs[(r * 256 + wv * 64) * 8]);
        }
        __syncthreads();
        #pragma unroll
        for (int t = 0; t < 2; ++t) {
            bf16x8 af[4], bfr[4];
            #pragma unroll
            for (int i = 0; i < 4; ++i)
                af[i] = *(const bf16x8*)&As[swz64(wm + i * 16 + l15, t * 4 + quad)];
            #pragma unroll
            for (int j = 0; j < 4; ++j)
                bfr[j] = *(const bf16x8*)&Bs[swz64(wn + j * 16 + l15, t * 4 + quad)];
            #pragma unroll
            for (int i = 0; i < 4; ++i)
                #pragma unroll
                for (int j = 0; j < 4; ++j)
                    acc[i][j] = __builtin_amdgcn_mfma_f32_16x16x32_bf16(af[i], bfr[j], acc[i][j], 0, 0, 0);
        }
    }

    #pragma unroll
    for (int i = 0; i < 4; ++i) {
        #pragma unroll
        for (int j = 0; j < 4; ++j) {
            int col = nBase + wn + j * 16 + l15;
            float bcol = bias[col];
            if (MODE == 2) {
                int hh = col >> 6, dk = col & 63;
                int row0 = mBase + wm + i * 16 + quad * 4;
                int bb = row0 >> 10, s = row0 & 1023;
                ushort4 v4;
                v4.x = f2bf(acc[i][j][0] + bcol);
                v4.y = f2bf(acc[i][j][1] + bcol);
                v4.z = f2bf(acc[i][j][2] + bcol);
                v4.w = f2bf(acc[i][j][3] + bcol);
                *(ushort4*)&Cb[((size_t)((bb * HH + hh) * DKK) + dk) * SS + s] = v4;
            } else {
                #pragma unroll
                for (int r = 0; r < 4; ++r) {
                    int row = mBase + wm + i * 16 + quad * 4 + r;
                    float v = acc[i][j][r] + bcol;
                    if (MODE == 1) Cf[(size_t)row * N + col] = v;
                    else           Cb[(size_t)row * N + col] = f2bf(v);
                }
            }
        }
    }
}

__global__ __launch_bounds__(256) void gemm_qkv_kernel(
    const u16* __restrict__ Xq, const u16* __restrict__ Xk, const u16* __restrict__ Xv,
    const u16* __restrict__ Wq, const u16* __restrict__ Wk, const u16* __restrict__ Wv,
    const float* __restrict__ bq, const float* __restrict__ bk, const float* __restrict__ bv,
    u16* __restrict__ Cq, u16* __restrict__ Ck, u16* __restrict__ Vtout)
{
    __shared__ __align__(16) u16 As[128 * 64];
    __shared__ __align__(16) u16 Bs[128 * 64];

    // T1 bijective XCD swizzle: 768 blocks (768%8==0), chunk = 96.
    const int lin = blockIdx.x + 8 * blockIdx.y + 256 * blockIdx.z;   // 0..767
    const int sw  = (lin & 7) * 96 + (lin >> 3);
    const int x = sw & 7, y = (sw >> 3) & 31, z = sw >> 8;
    const int mBase = y * 128, nBase = x * 128;

    if (z == 2) {
        gemm_body<2>(Xv, Wv, bv, Vtout, nullptr, mBase, nBase, As, Bs);
    } else {
        const u16* A = (z == 0) ? Xq : Xk;
        const u16* W = (z == 0) ? Wq : Wk;
        const float* bias = (z == 0) ? bq : bk;
        u16* C = (z == 0) ? Cq : Ck;
        gemm_body<0>(A, W, bias, C, nullptr, mBase, nBase, As, Bs);
    }
}

__global__ __launch_bounds__(256) void gemm_out_kernel(
    const u16* __restrict__ A, const u16* __restrict__ W,
    const float* __restrict__ bias, float* __restrict__ Cf)
{
    __shared__ __align__(16) u16 As[128 * 64];
    __shared__ __align__(16) u16 Bs[128 * 64];

    // 256 blocks, chunk = 32
    const int lin = blockIdx.x + 8 * blockIdx.y;                      // 0..255
    const int sw  = (lin & 7) * 32 + (lin >> 3);
    const int x = sw & 7, y = sw >> 3;
    gemm_body<1>(A, W, bias, nullptr, Cf, y * 128, x * 128, As, Bs);
}

// ---------------------------------------------------------------------------
// 3) Flash attention, QT=64, transposed-S variant (unchanged from round 5:
//    single-buffer K/V LDS staging + XCD swizzle + fragment-order bias +
//    operand-swapped PV giving lane-local rsum and ushort4 epilogue).
// ---------------------------------------------------------------------------
__global__ __launch_bounds__(256) void attn_kernel(
    const u16* __restrict__ Qf, const u16* __restrict__ Kf,
    const u16* __restrict__ Vt, const u16* __restrict__ biasT,
    u16* __restrict__ Attn)
{
    __shared__ __align__(16) u16 Qs[64 * 64];
    __shared__ __align__(16) u16 Ks[64 * 64];
    __shared__ __align__(16) u16 Vs[64 * 64];      // [dk][ks] swizzled
    __shared__ __align__(16) u16 Ps[4][16 * 72];   // per-wave [q][k], +8 pad
    const int tid = threadIdx.x;
    const int wv = tid >> 6, ln = tid & 63, l15 = ln & 15, quad = ln >> 4;

    // T1: bijective XCD swizzle (1024 blocks, 1024%8==0).
    const int lin = blockIdx.x + 16 * blockIdx.y + 256 * blockIdx.z;  // 0..1023
    const int sw  = (lin & 7) * 128 + (lin >> 3);
    const int qt = sw & 15, h = (sw >> 4) & 15, b = sw >> 8;
    const int q0 = qt * 64;

    // 64x64-u16 staging map (8 chunks/row)
    int row64[2], col64[2];
    #pragma unroll
    for (int r = 0; r < 2; ++r) {
        int p = r * 256 + wv * 64 + ln;
        row64[r] = p >> 3;
        col64[r] = ((p & 7) ^ (row64[r] & 7)) * 8;
    }

    // stage Q tile [64 q][64 dk]
    #pragma unroll
    for (int r = 0; r < 2; ++r)
        load16_lds(Qf + ((size_t)(b * SS + q0 + row64[r])) * DD + h * DKK + col64[r],
                   &Qs[(r * 256 + wv * 64) * 8]);
    __syncthreads();

    // loop-invariant Q fragments (B-operand in QK^T)
    bf16x8 aq[2];
    #pragma unroll
    for (int t = 0; t < 2; ++t)
        aq[t] = *(const bf16x8*)&Qs[swz64(wv * 16 + l15, t * 4 + quad)];

    const size_t vt_head = ((size_t)(b * HH + h)) * DKK * SS;
    const u16* Kp[2]; const u16* Vp[2];
    #pragma unroll
    for (int r = 0; r < 2; ++r) {
        Kp[r] = Kf + ((size_t)(b * SS + row64[r])) * DD + h * DKK + col64[r];
        Vp[r] = Vt + vt_head + (size_t)row64[r] * SS + col64[r];
    }

    // bias: fragment-order layout [b][kt][j][quad][q][4]; per-lane base
    const int qq = q0 + wv * 16 + l15;
    const u16* bpT = biasT + (size_t)b * 1048576 + (size_t)quad * 4096 + (size_t)qq * 4;

    floatx4 o[4] = {};
    float rsum = 0.f;

    for (int kt = 0; kt < 16; ++kt) {
        const int kk0 = kt * 64;
        __syncthreads();    // prior-iteration K/V LDS reads complete
        #pragma unroll
        for (int r = 0; r < 2; ++r) {
            load16_lds(Kp[r] + (size_t)kk0 * DD, &Ks[(r * 256 + wv * 64) * 8]);
            load16_lds(Vp[r] + kk0, &Vs[(r * 256 + wv * 64) * 8]);
        }
        __syncthreads();    // staging complete

        // bias loads: 4 coalesced uint2, latency hides under QK MFMAs
        uint2 braw[4];
        #pragma unroll
        for (int j = 0; j < 4; ++j)
            braw[j] = *(const uint2*)&bpT[(size_t)kt * 65536 + j * 16384];

        // S^T = K Q^T : row = k-within-16 (quad*4+r), col = q (l15)
        floatx4 sfr[4];
        #pragma unroll
        for (int j = 0; j < 4; ++j) {
            bf16x8 bk0 = *(const bf16x8*)&Ks[swz64(j * 16 + l15, quad)];
            bf16x8 bk1 = *(const bf16x8*)&Ks[swz64(j * 16 + l15, 4 + quad)];
            floatx4 s = {};
            s = __builtin_amdgcn_mfma_f32_16x16x32_bf16(bk0, aq[0], s, 0, 0, 0);
            sfr[j] = __builtin_amdgcn_mfma_f32_16x16x32_bf16(bk1, aq[1], s, 0, 0, 0);
        }

        // softmax: p = exp2(s*0.1803.. + bias2); packed b64 P-stores
        #pragma unroll
        for (int j = 0; j < 4; ++j) {
            float b0 = __uint_as_float(braw[j].x << 16);
            float b1 = __uint_as_float(braw[j].x & 0xffff0000u);
            float b2 = __uint_as_float(braw[j].y << 16);
            float b3 = __uint_as_float(braw[j].y & 0xffff0000u);
            float p0 = __builtin_amdgcn_exp2f(fmaf(sfr[j][0], QKSCALE, b0));
            float p1 = __builtin_amdgcn_exp2f(fmaf(sfr[j][1], QKSCALE, b1));
            float p2 = __builtin_amdgcn_exp2f(fmaf(sfr[j][2], QKSCALE, b2));
            float p3 = __builtin_amdgcn_exp2f(fmaf(sfr[j][3], QKSCALE, b3));
            rsum += (p0 + p1) + (p2 + p3);
            uint2 pk;
            pk.x = (__float_as_uint(p0) >> 16) | (__float_as_uint(p1) & 0xffff0000u);
            pk.y = (__float_as_uint(p2) >> 16) | (__float_as_uint(p3) & 0xffff0000u);
            *(uint2*)&Ps[wv][l15 * 72 + j * 16 + quad * 4] = pk;
        }

        // O^T += V^T P^T  (operand-swapped: A=V-frag, B=P-frag; Ps wave-private)
        #pragma unroll
        for (int t = 0; t < 2; ++t) {
            bf16x8 ap = *(const bf16x8*)&Ps[wv][l15 * 72 + t * 32 + quad * 8];
            #pragma unroll
            for (int j = 0; j < 4; ++j) {
                bf16x8 bvv = *(const bf16x8*)&Vs[swz64(j * 16 + l15, t * 4 + quad)];
                o[j] = __builtin_amdgcn_mfma_f32_16x16x32_bf16(bvv, ap, o[j], 0, 0, 0);
            }
        }
    }

    // rsum: butterfly over quads (bits 4,5) -> every lane holds the full
    // row-sum for its own q = l15.  No LDS bounce needed.
    rsum += __shfl_xor(rsum, 16);
    rsum += __shfl_xor(rsum, 32);
    const float ri = 1.0f / rsum;

    // epilogue: o[j][r] = O[q=qq][dk = j*16 + quad*4 + r] -> 4 ushort4 stores
    u16* outp = Attn + ((size_t)(b * SS + qq)) * DD + h * DKK + quad * 4;
    #pragma unroll
    for (int j = 0; j < 4; ++j) {
        ushort4 v4;
        v4.x = f2bf(o[j][0] * ri);
        v4.y = f2bf(o[j][1] * ri);
        v4.z = f2bf(o[j][2] * ri);
        v4.w = f2bf(o[j][3] * ri);
        *(ushort4*)&outp[j * 16] = v4;
    }
}

// ---------------------------------------------------------------------------
// launch
// ---------------------------------------------------------------------------
extern "C" void kernel_launch(void* const* d_in, const int* in_sizes, int n_in,
                              void* d_out, int out_size, void* d_ws, size_t ws_size,
                              hipStream_t stream)
{
    const float* Qx  = (const float*)d_in[0];
    const float* Kx  = (const float*)d_in[1];
    const float* Vx  = (const float*)d_in[2];
    const float* prob = (const float*)d_in[3];
    const int*   mask = (const int*)d_in[4];
    const int*   lam  = (const int*)d_in[5];
    const float* Wq  = (const float*)d_in[6];
    const float* bq  = (const float*)d_in[7];
    const float* Wk  = (const float*)d_in[8];
    const float* bk  = (const float*)d_in[9];
    const float* Wv  = (const float*)d_in[10];
    const float* bv  = (const float*)d_in[11];
    const float* Wo  = (const float*)d_in[12];
    const float* bo  = (const float*)d_in[13];

    char* ws = (char*)d_ws;
    const size_t MB = 1024 * 1024;
    u16*   Xq     = (u16*)(ws + 0 * MB);
    u16*   Xk     = (u16*)(ws + 8 * MB);
    u16*   Xv     = (u16*)(ws + 16 * MB);
    u16*   wq     = (u16*)(ws + 24 * MB);
    u16*   wk     = (u16*)(ws + 26 * MB);
    u16*   wvp    = (u16*)(ws + 28 * MB);
    u16*   wo     = (u16*)(ws + 30 * MB);
    u16*   q_flat = (u16*)(ws + 32 * MB);
    u16*   k_flat = (u16*)(ws + 40 * MB);
    u16*   vt     = (u16*)(ws + 56 * MB);
    u16*   biasT  = (u16*)(ws + 64 * MB);   // 8MB bf16 [b][kt][j][quad][q][4], prescaled by log2e
    u16*   attn   = (u16*)(ws + 80 * MB);

    float* maskOut = (out_size >= 2 * BB * SS * DD) ? (float*)d_out + (size_t)BB * SS * DD
                                                    : nullptr;

    prep_kernel<<<5120, 256, 0, stream>>>(Qx, Kx, Vx, Wq, Wk, Wv, Wo, prob, mask, lam,
                                          Xq, Xk, Xv, wq, wk, wvp, wo, biasT, maskOut);
    gemm_qkv_kernel<<<dim3(8, 32, 3), 256, 0, stream>>>(Xq, Xk, Xv, wq, wk, wvp,
                                                        bq, bk, bv, q_flat, k_flat, vt);
    attn_kernel<<<dim3(16, 16, 4), 256, 0, stream>>>(q_flat, k_flat, vt, biasT, attn);
    gemm_out_kernel<<<dim3(8, 32, 1), 256, 0, stream>>>(attn, wo, bo, (float*)d_out);
}

// Round 10
// 242.429 us; speedup vs baseline: 1.0342x; 1.0250x over previous
//
#include <hip/hip_runtime.h>
#include <hip/hip_bf16.h>
#include <cstdint>
#include <cstddef>

// Problem constants
#define BB 4
#define SS 1024
#define DD 1024
#define HH 16
#define DKK 64

typedef unsigned short u16;
typedef __bf16 bf16_t;
typedef __attribute__((ext_vector_type(8))) bf16_t bf16x8;
typedef __attribute__((ext_vector_type(4))) float floatx4;

#define LOG2E 1.4426950408889634f
#define QKSCALE 0.18033688011112042f   // 0.125 * log2(e)

// fp32 -> bf16 round-to-nearest-even
static __device__ inline u16 f2bf(float f) {
    union { float f; unsigned u; } v; v.f = f;
    unsigned r = v.u + 0x7fffu + ((v.u >> 16) & 1u);
    return (u16)(r >> 16);
}

// async global->LDS, 16B per lane. LDS dest must be wave-uniform base; HW adds lane*16.
static __device__ inline void load16_lds(const void* g, void* l) {
    __builtin_amdgcn_global_load_lds(
        (const __attribute__((address_space(1))) unsigned int*)g,
        (__attribute__((address_space(3))) unsigned int*)l,
        16, 0, 0);
}

// XOR-swizzled LDS u16 index for (row, 16B-chunk) tiles.
static __device__ inline int swz64(int row, int c) { return row * 64 + ((c ^ (row & 7)) * 8); }
static __device__ inline int swz32(int row, int c) { return row * 32 + ((c ^ ((row >> 1) & 3)) * 8); }

static __device__ inline float lam_val(const int* p) {
    int v = *p;
    if (v >= -100000 && v <= 100000) return (float)v;   // stored as int32
    union { int i; float f; } u; u.i = v; return u.f;    // hedge: stored as fp32 bits
}

// ---------------------------------------------------------------------------
// 1) prep (unchanged from round 9): bias transpose + fp32->bf16 conversion.
// ---------------------------------------------------------------------------
__global__ void prep_kernel(const float* __restrict__ Qx, const float* __restrict__ Kx,
                            const float* __restrict__ Vx,
                            const float* __restrict__ Wq, const float* __restrict__ Wk,
                            const float* __restrict__ Wv, const float* __restrict__ Wo,
                            const float* __restrict__ prob, const int* __restrict__ mask,
                            const int* __restrict__ lam_p,
                            u16* __restrict__ Xq, u16* __restrict__ Xk, u16* __restrict__ Xv,
                            u16* __restrict__ wq, u16* __restrict__ wk,
                            u16* __restrict__ wv, u16* __restrict__ wo,
                            u16* __restrict__ biasT, float* __restrict__ maskOut)
{
    __shared__ union {
        float tile[64][65];     // 16640 B
        u16   btile[64][68];    //  8704 B (reused after barrier)
    } sh;
    const int blk = blockIdx.x, tid = threadIdx.x;

    if (blk >= 1024) {
        const int cb = blk - 1024;
        const int base = cb * 1024;            // float4 units
        const float* src; u16* dst; int off0;
        if (base < 3145728) {
            int s = base >> 20;  off0 = base & 1048575;
            src = (s == 0) ? Qx : (s == 1) ? Kx : Vx;
            dst = (s == 0) ? Xq : (s == 1) ? Xk : Xv;
        } else {
            int v2 = base - 3145728;
            int s = v2 >> 18;  off0 = v2 & 262143;
            src = (s == 0) ? Wq : (s == 1) ? Wk : (s == 2) ? Wv : Wo;
            dst = (s == 0) ? wq : (s == 1) ? wk : (s == 2) ? wv : wo;
        }
        const float4* s4 = (const float4*)src;
        #pragma unroll
        for (int r = 0; r < 2; ++r) {
            int i4 = off0 + r * 512 + tid * 2;   // pair of consecutive float4
            float4 a  = s4[i4];
            float4 b2 = s4[i4 + 1];
            uint4 pk;
            pk.x = (unsigned)f2bf(a.x)  | ((unsigned)f2bf(a.y)  << 16);
            pk.y = (unsigned)f2bf(a.z)  | ((unsigned)f2bf(a.w)  << 16);
            pk.z = (unsigned)f2bf(b2.x) | ((unsigned)f2bf(b2.y) << 16);
            pk.w = (unsigned)f2bf(b2.z) | ((unsigned)f2bf(b2.w) << 16);
            *(uint4*)((ushort4*)dst + i4) = pk;   // 16B coalesced store
        }
        return;
    }

    // bias branch: 1024 blocks, 64x64 tile (q-tile q0, k-tile k0 = kt*64)
    const int b = blk >> 8;
    const int q0 = ((blk >> 4) & 15) * 64, k0 = (blk & 15) * 64;
    const int kt = blk & 15;
    #pragma unroll
    for (int rr = 0; rr < 4; ++rr) {
        int unit = rr * 256 + tid;
        int kl = unit >> 4, qi = unit & 15;
        float4 p4 = *(const float4*)&prob[((size_t)(b * SS + k0 + kl)) * SS + q0 + qi * 4];
        sh.tile[kl][qi * 4 + 0] = p4.x;
        sh.tile[kl][qi * 4 + 1] = p4.y;
        sh.tile[kl][qi * 4 + 2] = p4.z;
        sh.tile[kl][qi * 4 + 3] = p4.w;
    }
    __syncthreads();
    const float lamc = lam_val(lam_p) * LOG2E;
    ushort4 bbv[4];
    int qv[4], k4v[4];
    #pragma unroll
    for (int rr = 0; rr < 4; ++rr) {
        int pair = rr * 256 + tid;
        int q = pair >> 4, k4 = pair & 15;
        qv[rr] = q; k4v[rr] = k4;
        size_t midx = ((size_t)(b * SS + q0 + q)) * SS + k0 + k4 * 4;
        int4 m4 = *(const int4*)&mask[midx];
        float p0 = sh.tile[k4 * 4 + 0][q];
        float p1 = sh.tile[k4 * 4 + 1][q];
        float p2 = sh.tile[k4 * 4 + 2][q];
        float p3 = sh.tile[k4 * 4 + 3][q];
        bbv[rr].x = f2bf((m4.x == 0) ? -1.5e9f : -lamc * p0);
        bbv[rr].y = f2bf((m4.y == 0) ? -1.5e9f : -lamc * p1);
        bbv[rr].z = f2bf((m4.z == 0) ? -1.5e9f : -lamc * p2);
        bbv[rr].w = f2bf((m4.w == 0) ? -1.5e9f : -lamc * p3);
        if (maskOut) {
            float4 mf = { (float)m4.x, (float)m4.y, (float)m4.z, (float)m4.w };
            *(float4*)&maskOut[midx] = mf;
        }
    }
    __syncthreads();    // all tile reads complete; safe to reuse storage
    #pragma unroll
    for (int rr = 0; rr < 4; ++rr)
        *(ushort4*)&sh.btile[qv[rr]][k4v[rr] * 4] = bbv[rr];
    __syncthreads();
    // coalesced biasT write: [b][kt][j][quad][q(1024 global)][4] u16
    u16* bT = biasT + (size_t)(b * 16 + kt) * 65536;
    #pragma unroll
    for (int rr = 0; rr < 4; ++rr) {
        int idx = rr * 256 + tid;                 // (j, quad, q_local)
        int j = idx >> 8, quad = (idx >> 6) & 3, ql = idx & 63;
        ushort4 v = *(const ushort4*)&sh.btile[ql][j * 16 + quad * 4];
        *(ushort4*)&bT[(size_t)((j * 4 + quad) * 1024 + q0 + ql) * 4] = v;
    }
}

// ---------------------------------------------------------------------------
// 2a) gemm_qkv: 128x128 tile, BK=32 double-buffered (static buffer names).
//     Residency math (round-8 lesson): LDS 4x(128x32x2B) = 32 KB -> 3+
//     blocks/CU; registers ~(84+dbuf overhead) VGPR + 64 acc < 170.7
//     boundary -> 3 waves/SIMD, pinned by __launch_bounds__(256,3).
//     Per 32-K tile: issue stage(t+1) -> 16 MFMAs on tile t -> one barrier;
//     the L2 staging drain overlaps the compute phase instead of being
//     fully exposed (rounds 2/8 failed on alias-drain / register-cliff,
//     both addressed here).
// ---------------------------------------------------------------------------
template <int MODE>
static __device__ inline void gemm_body32(const u16* __restrict__ A, const u16* __restrict__ W,
                                          const float* __restrict__ bias,
                                          u16* __restrict__ Cb, float* __restrict__ Cf,
                                          int mBase, int nBase,
                                          u16* As0, u16* Bs0, u16* As1, u16* Bs1)
{
    constexpr int K = 1024, N = 1024;
    const int tid = threadIdx.x;
    const int wv = tid >> 6, ln = tid & 63, l15 = ln & 15, quad = ln >> 4;
    const int wm = (wv & 1) * 64, wn = (wv >> 1) * 64;

    // 128x32-u16 staging map: 512 units of 16B, 4 chunks/row, 2 rounds/wave
    const u16* Aptr[2]; const u16* Wptr[2];
    #pragma unroll
    for (int r = 0; r < 2; ++r) {
        int p = r * 256 + wv * 64 + ln;     // 0..511
        int row = p >> 2;                   // 0..127
        int c = (p & 3) ^ ((row >> 1) & 3);
        Aptr[r] = A + (size_t)(mBase + row) * K + c * 8;
        Wptr[r] = W + (size_t)(nBase + row) * K + c * 8;
    }

    floatx4 acc[4][4] = {};

#define G_STAGE32(k0, Ad, Bd)                                            \
    {                                                                    \
        _Pragma("unroll")                                                \
        for (int r = 0; r < 2; ++r) {                                    \
            load16_lds(Aptr[r] + (k0), &Ad[(r * 256 + wv * 64) * 8]);    \
            load16_lds(Wptr[r] + (k0), &Bd[(r * 256 + wv * 64) * 8]);    \
        }                                                                \
    }

#define G_COMPUTE32(Asrc, Bsrc)                                          \
    {                                                                    \
        bf16x8 af[4], bfr[4];                                            \
        _Pragma("unroll")                                                \
        for (int i = 0; i < 4; ++i)                                      \
            af[i] = *(const bf16x8*)&Asrc[swz32(wm + i * 16 + l15, quad)]; \
        _Pragma("unroll")                                                \
        for (int j = 0; j < 4; ++j)                                      \
            bfr[j] = *(const bf16x8*)&Bsrc[swz32(wn + j * 16 + l15, quad)]; \
        _Pragma("unroll")                                                \
        for (int i = 0; i < 4; ++i)                                      \
            _Pragma("unroll")                                            \
            for (int j = 0; j < 4; ++j)                                  \
                acc[i][j] = __builtin_amdgcn_mfma_f32_16x16x32_bf16(af[i], bfr[j], acc[i][j], 0, 0, 0); \
    }

    // prologue: stage k=0 into buf0; drain
    G_STAGE32(0, As0, Bs0);
    __syncthreads();

    for (int k0 = 0; k0 < K; k0 += 64) {
        if (k0 + 32 < K) G_STAGE32(k0 + 32, As1, Bs1);
        G_COMPUTE32(As0, Bs0);
        __syncthreads();            // prefetch landed + buf0 reads done
        if (k0 + 64 < K) G_STAGE32(k0 + 64, As0, Bs0);
        G_COMPUTE32(As1, Bs1);
        __syncthreads();            // prefetch landed + buf1 reads done
    }
#undef G_STAGE32
#undef G_COMPUTE32

    #pragma unroll
    for (int i = 0; i < 4; ++i) {
        #pragma unroll
        for (int j = 0; j < 4; ++j) {
            int col = nBase + wn + j * 16 + l15;
            float bcol = bias[col];
            if (MODE == 2) {
                int hh = col >> 6, dk = col & 63;
                int row0 = mBase + wm + i * 16 + quad * 4;
                int bb = row0 >> 10, s = row0 & 1023;
                ushort4 v4;
                v4.x = f2bf(acc[i][j][0] + bcol);
                v4.y = f2bf(acc[i][j][1] + bcol);
                v4.z = f2bf(acc[i][j][2] + bcol);
                v4.w = f2bf(acc[i][j][3] + bcol);
                *(ushort4*)&Cb[((size_t)((bb * HH + hh) * DKK) + dk) * SS + s] = v4;
            } else {
                #pragma unroll
                for (int r = 0; r < 4; ++r) {
                    int row = mBase + wm + i * 16 + quad * 4 + r;
                    float v = acc[i][j][r] + bcol;
                    (void)Cf;
                    Cb[(size_t)row * N + col] = f2bf(v);
                }
            }
        }
    }
}

__global__ __launch_bounds__(256, 3) void gemm_qkv_kernel(
    const u16* __restrict__ Xq, const u16* __restrict__ Xk, const u16* __restrict__ Xv,
    const u16* __restrict__ Wq, const u16* __restrict__ Wk, const u16* __restrict__ Wv,
    const float* __restrict__ bq, const float* __restrict__ bk, const float* __restrict__ bv,
    u16* __restrict__ Cq, u16* __restrict__ Ck, u16* __restrict__ Vtout)
{
    __shared__ __align__(16) u16 As0[128 * 32];
    __shared__ __align__(16) u16 Bs0[128 * 32];
    __shared__ __align__(16) u16 As1[128 * 32];
    __shared__ __align__(16) u16 Bs1[128 * 32];

    // T1 bijective XCD swizzle: 768 blocks (768%8==0), chunk = 96.
    const int lin = blockIdx.x + 8 * blockIdx.y + 256 * blockIdx.z;   // 0..767
    const int sw  = (lin & 7) * 96 + (lin >> 3);
    const int x = sw & 7, y = (sw >> 3) & 31, z = sw >> 8;
    const int mBase = y * 128, nBase = x * 128;

    if (z == 2) {
        gemm_body32<2>(Xv, Wv, bv, Vtout, nullptr, mBase, nBase, As0, Bs0, As1, Bs1);
    } else {
        const u16* A = (z == 0) ? Xq : Xk;
        const u16* W = (z == 0) ? Wq : Wk;
        const float* bias = (z == 0) ? bq : bk;
        u16* C = (z == 0) ? Cq : Ck;
        gemm_body32<0>(A, W, bias, C, nullptr, mBase, nBase, As0, Bs0, As1, Bs1);
    }
}

// ---------------------------------------------------------------------------
// 2b) gemm_out: BM=64 x BN=128 tiles -> 512 blocks = 2 blocks/CU (was 256 =
//     1 block/CU, the most occupancy-starved kernel in the pipeline).  Waves
//     split 1M x 4N: per-wave 64x32 output, acc[4][2] = 32 AGPRs.  BK=64
//     single-buffer (round-7-verified staging/swz64 involution).
// ---------------------------------------------------------------------------
__global__ __launch_bounds__(256) void gemm_out_kernel(
    const u16* __restrict__ A, const u16* __restrict__ W,
    const float* __restrict__ bias, float* __restrict__ Cf)
{
    constexpr int K = 1024, N = 1024;
    __shared__ __align__(16) u16 As[64 * 64];     //  8 KB
    __shared__ __align__(16) u16 Bs[128 * 64];    // 16 KB
    const int tid = threadIdx.x;
    const int wv = tid >> 6, ln = tid & 63, l15 = ln & 15, quad = ln >> 4;
    const int wn = wv * 32;

    // 512 blocks (8 x, 64 y), XCD swizzle chunk = 64
    const int lin = blockIdx.x + 8 * blockIdx.y;                      // 0..511
    const int sw  = (lin & 7) * 64 + (lin >> 3);
    const int x = sw & 7, y = sw >> 3;
    const int mBase = y * 64, nBase = x * 128;

    // A staging: 64x64 u16 = 512 16B-units, 2 rounds; B: 128x64 = 4 rounds
    const u16* Aptr[2]; const u16* Wptr[4];
    #pragma unroll
    for (int r = 0; r < 2; ++r) {
        int p = r * 256 + wv * 64 + ln;     // 0..511
        int row = p >> 3;                   // 0..63
        int c = (p & 7) ^ (row & 7);
        Aptr[r] = A + (size_t)(mBase + row) * K + c * 8;
    }
    #pragma unroll
    for (int r = 0; r < 4; ++r) {
        int p = r * 256 + wv * 64 + ln;     // 0..1023
        int row = p >> 3;                   // 0..127
        int c = (p & 7) ^ (row & 7);
        Wptr[r] = W + (size_t)(nBase + row) * K + c * 8;
    }

    floatx4 acc[4][2] = {};

    for (int k0 = 0; k0 < K; k0 += 64) {
        __syncthreads();
        #pragma unroll
        for (int r = 0; r < 2; ++r)
            load16_lds(Aptr[r] + k0, &As[(r * 256 + wv * 64) * 8]);
        #pragma unroll
        for (int r = 0; r < 4; ++r)
            load16_lds(Wptr[r] + k0, &Bs[(r * 256 + wv * 64) * 8]);
        __syncthreads();
        #pragma unroll
        for (int t = 0; t < 2; ++t) {
            bf16x8 af[4], bfr[2];
            #pragma unroll
            for (int i = 0; i < 4; ++i)
                af[i] = *(const bf16x8*)&As[swz64(i * 16 + l15, t * 4 + quad)];
            #pragma unroll
            for (int j = 0; j < 2; ++j)
                bfr[j] = *(const bf16x8*)&Bs[swz64(wn + j * 16 + l15, t * 4 + quad)];
            #pragma unroll
            for (int i = 0; i < 4; ++i)
                #pragma unroll
                for (int j = 0; j < 2; ++j)
                    acc[i][j] = __builtin_amdgcn_mfma_f32_16x16x32_bf16(af[i], bfr[j], acc[i][j], 0, 0, 0);
        }
    }

    #pragma unroll
    for (int i = 0; i < 4; ++i) {
        #pragma unroll
        for (int j = 0; j < 2; ++j) {
            int col = nBase + wn + j * 16 + l15;
            float bcol = bias[col];
            #pragma unroll
            for (int r = 0; r < 4; ++r) {
                int row = mBase + i * 16 + quad * 4 + r;
                Cf[(size_t)row * N + col] = acc[i][j][r] + bcol;
            }
        }
    }
}

// ---------------------------------------------------------------------------
// 3) Flash attention (unchanged from round 5): single-buffer K/V staging +
//    XCD swizzle + fragment-order bias + operand-swapped PV.
// ---------------------------------------------------------------------------
__global__ __launch_bounds__(256) void attn_kernel(
    const u16* __restrict__ Qf, const u16* __restrict__ Kf,
    const u16* __restrict__ Vt, const u16* __restrict__ biasT,
    u16* __restrict__ Attn)
{
    __shared__ __align__(16) u16 Qs[64 * 64];
    __shared__ __align__(16) u16 Ks[64 * 64];
    __shared__ __align__(16) u16 Vs[64 * 64];      // [dk][ks] swizzled
    __shared__ __align__(16) u16 Ps[4][16 * 72];   // per-wave [q][k], +8 pad
    const int tid = threadIdx.x;
    const int wv = tid >> 6, ln = tid & 63, l15 = ln & 15, quad = ln >> 4;

    // T1: bijective XCD swizzle (1024 blocks, 1024%8==0).
    const int lin = blockIdx.x + 16 * blockIdx.y + 256 * blockIdx.z;  // 0..1023
    const int sw  = (lin & 7) * 128 + (lin >> 3);
    const int qt = sw & 15, h = (sw >> 4) & 15, b = sw >> 8;
    const int q0 = qt * 64;

    // 64x64-u16 staging map (8 chunks/row)
    int row64[2], col64[2];
    #pragma unroll
    for (int r = 0; r < 2; ++r) {
        int p = r * 256 + wv * 64 + ln;
        row64[r] = p >> 3;
        col64[r] = ((p & 7) ^ (row64[r] & 7)) * 8;
    }

    // stage Q tile [64 q][64 dk]
    #pragma unroll
    for (int r = 0; r < 2; ++r)
        load16_lds(Qf + ((size_t)(b * SS + q0 + row64[r])) * DD + h * DKK + col64[r],
                   &Qs[(r * 256 + wv * 64) * 8]);
    __syncthreads();

    // loop-invariant Q fragments (B-operand in QK^T)
    bf16x8 aq[2];
    #pragma unroll
    for (int t = 0; t < 2; ++t)
        aq[t] = *(const bf16x8*)&Qs[swz64(wv * 16 + l15, t * 4 + quad)];

    const size_t vt_head = ((size_t)(b * HH + h)) * DKK * SS;
    const u16* Kp[2]; const u16* Vp[2];
    #pragma unroll
    for (int r = 0; r < 2; ++r) {
        Kp[r] = Kf + ((size_t)(b * SS + row64[r])) * DD + h * DKK + col64[r];
        Vp[r] = Vt + vt_head + (size_t)row64[r] * SS + col64[r];
    }

    // bias: fragment-order layout [b][kt][j][quad][q][4]; per-lane base
    const int qq = q0 + wv * 16 + l15;
    const u16* bpT = biasT + (size_t)b * 1048576 + (size_t)quad * 4096 + (size_t)qq * 4;

    floatx4 o[4] = {};
    float rsum = 0.f;

    for (int kt = 0; kt < 16; ++kt) {
        const int kk0 = kt * 64;
        __syncthreads();    // prior-iteration K/V LDS reads complete
        #pragma unroll
        for (int r = 0; r < 2; ++r) {
            load16_lds(Kp[r] + (size_t)kk0 * DD, &Ks[(r * 256 + wv * 64) * 8]);
            load16_lds(Vp[r] + kk0, &Vs[(r * 256 + wv * 64) * 8]);
        }
        __syncthreads();    // staging complete

        // bias loads: 4 coalesced uint2, latency hides under QK MFMAs
        uint2 braw[4];
        #pragma unroll
        for (int j = 0; j < 4; ++j)
            braw[j] = *(const uint2*)&bpT[(size_t)kt * 65536 + j * 16384];

        // S^T = K Q^T : row = k-within-16 (quad*4+r), col = q (l15)
        floatx4 sfr[4];
        #pragma unroll
        for (int j = 0; j < 4; ++j) {
            bf16x8 bk0 = *(const bf16x8*)&Ks[swz64(j * 16 + l15, quad)];
            bf16x8 bk1 = *(const bf16x8*)&Ks[swz64(j * 16 + l15, 4 + quad)];
            floatx4 s = {};
            s = __builtin_amdgcn_mfma_f32_16x16x32_bf16(bk0, aq[0], s, 0, 0, 0);
            sfr[j] = __builtin_amdgcn_mfma_f32_16x16x32_bf16(bk1, aq[1], s, 0, 0, 0);
        }

        // softmax: p = exp2(s*0.1803.. + bias2); packed b64 P-stores
        #pragma unroll
        for (int j = 0; j < 4; ++j) {
            float b0 = __uint_as_float(braw[j].x << 16);
            float b1 = __uint_as_float(braw[j].x & 0xffff0000u);
            float b2 = __uint_as_float(braw[j].y << 16);
            float b3 = __uint_as_float(braw[j].y & 0xffff0000u);
            float p0 = __builtin_amdgcn_exp2f(fmaf(sfr[j][0], QKSCALE, b0));
            float p1 = __builtin_amdgcn_exp2f(fmaf(sfr[j][1], QKSCALE, b1));
            float p2 = __builtin_amdgcn_exp2f(fmaf(sfr[j][2], QKSCALE, b2));
            float p3 = __builtin_amdgcn_exp2f(fmaf(sfr[j][3], QKSCALE, b3));
            rsum += (p0 + p1) + (p2 + p3);
            uint2 pk;
            pk.x = (__float_as_uint(p0) >> 16) | (__float_as_uint(p1) & 0xffff0000u);
            pk.y = (__float_as_uint(p2) >> 16) | (__float_as_uint(p3) & 0xffff0000u);
            *(uint2*)&Ps[wv][l15 * 72 + j * 16 + quad * 4] = pk;
        }

        // O^T += V^T P^T  (operand-swapped: A=V-frag, B=P-frag; Ps wave-private)
        #pragma unroll
        for (int t = 0; t < 2; ++t) {
            bf16x8 ap = *(const bf16x8*)&Ps[wv][l15 * 72 + t * 32 + quad * 8];
            #pragma unroll
            for (int j = 0; j < 4; ++j) {
                bf16x8 bvv = *(const bf16x8*)&Vs[swz64(j * 16 + l15, t * 4 + quad)];
                o[j] = __builtin_amdgcn_mfma_f32_16x16x32_bf16(bvv, ap, o[j], 0, 0, 0);
            }
        }
    }

    // rsum: butterfly over quads (bits 4,5) -> every lane holds the full
    // row-sum for its own q = l15.  No LDS bounce needed.
    rsum += __shfl_xor(rsum, 16);
    rsum += __shfl_xor(rsum, 32);
    const float ri = 1.0f / rsum;

    // epilogue: o[j][r] = O[q=qq][dk = j*16 + quad*4 + r] -> 4 ushort4 stores
    u16* outp = Attn + ((size_t)(b * SS + qq)) * DD + h * DKK + quad * 4;
    #pragma unroll
    for (int j = 0; j < 4; ++j) {
        ushort4 v4;
        v4.x = f2bf(o[j][0] * ri);
        v4.y = f2bf(o[j][1] * ri);
        v4.z = f2bf(o[j][2] * ri);
        v4.w = f2bf(o[j][3] * ri);
        *(ushort4*)&outp[j * 16] = v4;
    }
}

// ---------------------------------------------------------------------------
// launch
// ---------------------------------------------------------------------------
extern "C" void kernel_launch(void* const* d_in, const int* in_sizes, int n_in,
                              void* d_out, int out_size, void* d_ws, size_t ws_size,
                              hipStream_t stream)
{
    const float* Qx  = (const float*)d_in[0];
    const float* Kx  = (const float*)d_in[1];
    const float* Vx  = (const float*)d_in[2];
    const float* prob = (const float*)d_in[3];
    const int*   mask = (const int*)d_in[4];
    const int*   lam  = (const int*)d_in[5];
    const float* Wq  = (const float*)d_in[6];
    const float* bq  = (const float*)d_in[7];
    const float* Wk  = (const float*)d_in[8];
    const float* bk  = (const float*)d_in[9];
    const float* Wv  = (const float*)d_in[10];
    const float* bv  = (const float*)d_in[11];
    const float* Wo  = (const float*)d_in[12];
    const float* bo  = (const float*)d_in[13];

    char* ws = (char*)d_ws;
    const size_t MB = 1024 * 1024;
    u16*   Xq     = (u16*)(ws + 0 * MB);
    u16*   Xk     = (u16*)(ws + 8 * MB);
    u16*   Xv     = (u16*)(ws + 16 * MB);
    u16*   wq     = (u16*)(ws + 24 * MB);
    u16*   wk     = (u16*)(ws + 26 * MB);
    u16*   wvp    = (u16*)(ws + 28 * MB);
    u16*   wo     = (u16*)(ws + 30 * MB);
    u16*   q_flat = (u16*)(ws + 32 * MB);
    u16*   k_flat = (u16*)(ws + 40 * MB);
    u16*   vt     = (u16*)(ws + 56 * MB);
    u16*   biasT  = (u16*)(ws + 64 * MB);   // 8MB bf16 [b][kt][j][quad][q][4], prescaled by log2e
    u16*   attn   = (u16*)(ws + 80 * MB);

    float* maskOut = (out_size >= 2 * BB * SS * DD) ? (float*)d_out + (size_t)BB * SS * DD
                                                    : nullptr;

    prep_kernel<<<5120, 256, 0, stream>>>(Qx, Kx, Vx, Wq, Wk, Wv, Wo, prob, mask, lam,
                                          Xq, Xk, Xv, wq, wk, wvp, wo, biasT, maskOut);
    gemm_qkv_kernel<<<dim3(8, 32, 3), 256, 0, stream>>>(Xq, Xk, Xv, wq, wk, wvp,
                                                        bq, bk, bv, q_flat, k_flat, vt);
    attn_kernel<<<dim3(16, 16, 4), 256, 0, stream>>>(q_flat, k_flat, vt, biasT, attn);
    gemm_out_kernel<<<dim3(8, 64), 256, 0, stream>>>(attn, wo, bo, (float*)d_out);
}

// Round 11
// 240.757 us; speedup vs baseline: 1.0414x; 1.0069x over previous
//
#include <hip/hip_runtime.h>
#include <hip/hip_bf16.h>
#include <cstdint>
#include <cstddef>

// Problem constants
#define BB 4
#define SS 1024
#define DD 1024
#define HH 16
#define DKK 64

typedef unsigned short u16;
typedef __bf16 bf16_t;
typedef __attribute__((ext_vector_type(8))) bf16_t bf16x8;
typedef __attribute__((ext_vector_type(4))) float floatx4;

#define LOG2E 1.4426950408889634f
#define QKSCALE 0.18033688011112042f   // 0.125 * log2(e)

// fp32 -> bf16 round-to-nearest-even
static __device__ inline u16 f2bf(float f) {
    union { float f; unsigned u; } v; v.f = f;
    unsigned r = v.u + 0x7fffu + ((v.u >> 16) & 1u);
    return (u16)(r >> 16);
}

// async global->LDS, 16B per lane. LDS dest must be wave-uniform base; HW adds lane*16.
static __device__ inline void load16_lds(const void* g, void* l) {
    __builtin_amdgcn_global_load_lds(
        (const __attribute__((address_space(1))) unsigned int*)g,
        (__attribute__((address_space(3))) unsigned int*)l,
        16, 0, 0);
}

// XOR-swizzled LDS u16 index for (row, 16B-chunk) tiles.
static __device__ inline int swz64(int row, int c) { return row * 64 + ((c ^ (row & 7)) * 8); }
static __device__ inline int swz32(int row, int c) { return row * 32 + ((c ^ ((row >> 1) & 3)) * 8); }

static __device__ inline float lam_val(const int* p) {
    int v = *p;
    if (v >= -100000 && v <= 100000) return (float)v;   // stored as int32
    union { int i; float f; } u; u.i = v; return u.f;    // hedge: stored as fp32 bits
}

// ---------------------------------------------------------------------------
// 1) prep: bias transpose + fp32->bf16 conversion.  Round-11 ILP fix:
//    VGPR=24 showed the compiler serialized the load/convert/store rounds
//    (one 32B load in flight/thread -> latency-bound at 2.4 TB/s, VALU 5.5%).
//    Conversion branch now issues all FOUR float4 loads before any convert.
//    Bias branch hoists the 4 independent mask int4 loads (and maskOut
//    stores) ahead of the prob-tile staging barrier.
// ---------------------------------------------------------------------------
__global__ void prep_kernel(const float* __restrict__ Qx, const float* __restrict__ Kx,
                            const float* __restrict__ Vx,
                            const float* __restrict__ Wq, const float* __restrict__ Wk,
                            const float* __restrict__ Wv, const float* __restrict__ Wo,
                            const float* __restrict__ prob, const int* __restrict__ mask,
                            const int* __restrict__ lam_p,
                            u16* __restrict__ Xq, u16* __restrict__ Xk, u16* __restrict__ Xv,
                            u16* __restrict__ wq, u16* __restrict__ wk,
                            u16* __restrict__ wv, u16* __restrict__ wo,
                            u16* __restrict__ biasT, float* __restrict__ maskOut)
{
    __shared__ union {
        float tile[64][65];     // 16640 B
        u16   btile[64][68];    //  8704 B (reused after barrier)
    } sh;
    const int blk = blockIdx.x, tid = threadIdx.x;

    if (blk >= 1024) {
        const int cb = blk - 1024;
        const int base = cb * 1024;            // float4 units
        const float* src; u16* dst; int off0;
        if (base < 3145728) {
            int s = base >> 20;  off0 = base & 1048575;
            src = (s == 0) ? Qx : (s == 1) ? Kx : Vx;
            dst = (s == 0) ? Xq : (s == 1) ? Xk : Xv;
        } else {
            int v2 = base - 3145728;
            int s = v2 >> 18;  off0 = v2 & 262143;
            src = (s == 0) ? Wq : (s == 1) ? Wk : (s == 2) ? Wv : Wo;
            dst = (s == 0) ? wq : (s == 1) ? wk : (s == 2) ? wv : wo;
        }
        const float4* s4 = (const float4*)src;
        const int i4 = off0 + tid * 2;
        // issue ALL loads first (64B in flight per thread), then convert/store
        float4 a0 = s4[i4];
        float4 b0 = s4[i4 + 1];
        float4 a1 = s4[i4 + 512];
        float4 b1 = s4[i4 + 513];
        uint4 p0, p1;
        p0.x = (unsigned)f2bf(a0.x) | ((unsigned)f2bf(a0.y) << 16);
        p0.y = (unsigned)f2bf(a0.z) | ((unsigned)f2bf(a0.w) << 16);
        p0.z = (unsigned)f2bf(b0.x) | ((unsigned)f2bf(b0.y) << 16);
        p0.w = (unsigned)f2bf(b0.z) | ((unsigned)f2bf(b0.w) << 16);
        p1.x = (unsigned)f2bf(a1.x) | ((unsigned)f2bf(a1.y) << 16);
        p1.y = (unsigned)f2bf(a1.z) | ((unsigned)f2bf(a1.w) << 16);
        p1.z = (unsigned)f2bf(b1.x) | ((unsigned)f2bf(b1.y) << 16);
        p1.w = (unsigned)f2bf(b1.z) | ((unsigned)f2bf(b1.w) << 16);
        *(uint4*)((ushort4*)dst + i4)       = p0;   // 16B coalesced stores
        *(uint4*)((ushort4*)dst + i4 + 512) = p1;
        return;
    }

    // bias branch: 1024 blocks, 64x64 tile (q-tile q0, k-tile k0 = kt*64)
    const int b = blk >> 8;
    const int q0 = ((blk >> 4) & 15) * 64, k0 = (blk & 15) * 64;
    const int kt = blk & 15;

    // mask loads issued FIRST: independent of the prob tile, their HBM/L2
    // latency hides under the staging below; maskOut written immediately.
    int4 m4v[4];
    #pragma unroll
    for (int rr = 0; rr < 4; ++rr) {
        int pair = rr * 256 + tid;
        int q = pair >> 4, k4 = pair & 15;
        size_t midx = ((size_t)(b * SS + q0 + q)) * SS + k0 + k4 * 4;
        m4v[rr] = *(const int4*)&mask[midx];
    }
    #pragma unroll
    for (int rr = 0; rr < 4; ++rr) {
        int unit = rr * 256 + tid;
        int kl = unit >> 4, qi = unit & 15;
        float4 p4 = *(const float4*)&prob[((size_t)(b * SS + k0 + kl)) * SS + q0 + qi * 4];
        sh.tile[kl][qi * 4 + 0] = p4.x;
        sh.tile[kl][qi * 4 + 1] = p4.y;
        sh.tile[kl][qi * 4 + 2] = p4.z;
        sh.tile[kl][qi * 4 + 3] = p4.w;
    }
    if (maskOut) {
        #pragma unroll
        for (int rr = 0; rr < 4; ++rr) {
            int pair = rr * 256 + tid;
            int q = pair >> 4, k4 = pair & 15;
            size_t midx = ((size_t)(b * SS + q0 + q)) * SS + k0 + k4 * 4;
            float4 mf = { (float)m4v[rr].x, (float)m4v[rr].y,
                          (float)m4v[rr].z, (float)m4v[rr].w };
            *(float4*)&maskOut[midx] = mf;
        }
    }
    __syncthreads();
    const float lamc = lam_val(lam_p) * LOG2E;
    ushort4 bbv[4];
    #pragma unroll
    for (int rr = 0; rr < 4; ++rr) {
        int pair = rr * 256 + tid;
        int q = pair >> 4, k4 = pair & 15;
        float p0 = sh.tile[k4 * 4 + 0][q];
        float p1 = sh.tile[k4 * 4 + 1][q];
        float p2 = sh.tile[k4 * 4 + 2][q];
        float p3 = sh.tile[k4 * 4 + 3][q];
        bbv[rr].x = f2bf((m4v[rr].x == 0) ? -1.5e9f : -lamc * p0);
        bbv[rr].y = f2bf((m4v[rr].y == 0) ? -1.5e9f : -lamc * p1);
        bbv[rr].z = f2bf((m4v[rr].z == 0) ? -1.5e9f : -lamc * p2);
        bbv[rr].w = f2bf((m4v[rr].w == 0) ? -1.5e9f : -lamc * p3);
    }
    __syncthreads();    // all tile reads complete; safe to reuse storage
    #pragma unroll
    for (int rr = 0; rr < 4; ++rr) {
        int pair = rr * 256 + tid;
        int q = pair >> 4, k4 = pair & 15;
        *(ushort4*)&sh.btile[q][k4 * 4] = bbv[rr];
    }
    __syncthreads();
    // coalesced biasT write: [b][kt][j][quad][q(1024 global)][4] u16
    u16* bT = biasT + (size_t)(b * 16 + kt) * 65536;
    #pragma unroll
    for (int rr = 0; rr < 4; ++rr) {
        int idx = rr * 256 + tid;                 // (j, quad, q_local)
        int j = idx >> 8, quad = (idx >> 6) & 3, ql = idx & 63;
        ushort4 v = *(const ushort4*)&sh.btile[ql][j * 16 + quad * 4];
        *(ushort4*)&bT[(size_t)((j * 4 + quad) * 1024 + q0 + ql) * 4] = v;
    }
}

// ---------------------------------------------------------------------------
// 2a) gemm_qkv (unchanged from round 10 — verified win): 128x128 tile,
//     BK=32 double-buffered, static buffer names, 32 KB LDS, 3 waves/SIMD.
// ---------------------------------------------------------------------------
template <int MODE>
static __device__ inline void gemm_body32(const u16* __restrict__ A, const u16* __restrict__ W,
                                          const float* __restrict__ bias,
                                          u16* __restrict__ Cb, float* __restrict__ Cf,
                                          int mBase, int nBase,
                                          u16* As0, u16* Bs0, u16* As1, u16* Bs1)
{
    constexpr int K = 1024, N = 1024;
    const int tid = threadIdx.x;
    const int wv = tid >> 6, ln = tid & 63, l15 = ln & 15, quad = ln >> 4;
    const int wm = (wv & 1) * 64, wn = (wv >> 1) * 64;

    // 128x32-u16 staging map: 512 units of 16B, 4 chunks/row, 2 rounds/wave
    const u16* Aptr[2]; const u16* Wptr[2];
    #pragma unroll
    for (int r = 0; r < 2; ++r) {
        int p = r * 256 + wv * 64 + ln;     // 0..511
        int row = p >> 2;                   // 0..127
        int c = (p & 3) ^ ((row >> 1) & 3);
        Aptr[r] = A + (size_t)(mBase + row) * K + c * 8;
        Wptr[r] = W + (size_t)(nBase + row) * K + c * 8;
    }

    floatx4 acc[4][4] = {};

#define G_STAGE32(k0, Ad, Bd)                                            \
    {                                                                    \
        _Pragma("unroll")                                                \
        for (int r = 0; r < 2; ++r) {                                    \
            load16_lds(Aptr[r] + (k0), &Ad[(r * 256 + wv * 64) * 8]);    \
            load16_lds(Wptr[r] + (k0), &Bd[(r * 256 + wv * 64) * 8]);    \
        }                                                                \
    }

#define G_COMPUTE32(Asrc, Bsrc)                                          \
    {                                                                    \
        bf16x8 af[4], bfr[4];                                            \
        _Pragma("unroll")                                                \
        for (int i = 0; i < 4; ++i)                                      \
            af[i] = *(const bf16x8*)&Asrc[swz32(wm + i * 16 + l15, quad)]; \
        _Pragma("unroll")                                                \
        for (int j = 0; j < 4; ++j)                                      \
            bfr[j] = *(const bf16x8*)&Bsrc[swz32(wn + j * 16 + l15, quad)]; \
        _Pragma("unroll")                                                \
        for (int i = 0; i < 4; ++i)                                      \
            _Pragma("unroll")                                            \
            for (int j = 0; j < 4; ++j)                                  \
                acc[i][j] = __builtin_amdgcn_mfma_f32_16x16x32_bf16(af[i], bfr[j], acc[i][j], 0, 0, 0); \
    }

    // prologue: stage k=0 into buf0; drain
    G_STAGE32(0, As0, Bs0);
    __syncthreads();

    for (int k0 = 0; k0 < K; k0 += 64) {
        if (k0 + 32 < K) G_STAGE32(k0 + 32, As1, Bs1);
        G_COMPUTE32(As0, Bs0);
        __syncthreads();            // prefetch landed + buf0 reads done
        if (k0 + 64 < K) G_STAGE32(k0 + 64, As0, Bs0);
        G_COMPUTE32(As1, Bs1);
        __syncthreads();            // prefetch landed + buf1 reads done
    }
#undef G_STAGE32
#undef G_COMPUTE32

    #pragma unroll
    for (int i = 0; i < 4; ++i) {
        #pragma unroll
        for (int j = 0; j < 4; ++j) {
            int col = nBase + wn + j * 16 + l15;
            float bcol = bias[col];
            if (MODE == 2) {
                int hh = col >> 6, dk = col & 63;
                int row0 = mBase + wm + i * 16 + quad * 4;
                int bb = row0 >> 10, s = row0 & 1023;
                ushort4 v4;
                v4.x = f2bf(acc[i][j][0] + bcol);
                v4.y = f2bf(acc[i][j][1] + bcol);
                v4.z = f2bf(acc[i][j][2] + bcol);
                v4.w = f2bf(acc[i][j][3] + bcol);
                *(ushort4*)&Cb[((size_t)((bb * HH + hh) * DKK) + dk) * SS + s] = v4;
            } else {
                #pragma unroll
                for (int r = 0; r < 4; ++r) {
                    int row = mBase + wm + i * 16 + quad * 4 + r;
                    float v = acc[i][j][r] + bcol;
                    (void)Cf;
                    Cb[(size_t)row * N + col] = f2bf(v);
                }
            }
        }
    }
}

__global__ __launch_bounds__(256, 3) void gemm_qkv_kernel(
    const u16* __restrict__ Xq, const u16* __restrict__ Xk, const u16* __restrict__ Xv,
    const u16* __restrict__ Wq, const u16* __restrict__ Wk, const u16* __restrict__ Wv,
    const float* __restrict__ bq, const float* __restrict__ bk, const float* __restrict__ bv,
    u16* __restrict__ Cq, u16* __restrict__ Ck, u16* __restrict__ Vtout)
{
    __shared__ __align__(16) u16 As0[128 * 32];
    __shared__ __align__(16) u16 Bs0[128 * 32];
    __shared__ __align__(16) u16 As1[128 * 32];
    __shared__ __align__(16) u16 Bs1[128 * 32];

    // T1 bijective XCD swizzle: 768 blocks (768%8==0), chunk = 96.
    const int lin = blockIdx.x + 8 * blockIdx.y + 256 * blockIdx.z;   // 0..767
    const int sw  = (lin & 7) * 96 + (lin >> 3);
    const int x = sw & 7, y = (sw >> 3) & 31, z = sw >> 8;
    const int mBase = y * 128, nBase = x * 128;

    if (z == 2) {
        gemm_body32<2>(Xv, Wv, bv, Vtout, nullptr, mBase, nBase, As0, Bs0, As1, Bs1);
    } else {
        const u16* A = (z == 0) ? Xq : Xk;
        const u16* W = (z == 0) ? Wq : Wk;
        const float* bias = (z == 0) ? bq : bk;
        u16* C = (z == 0) ? Cq : Ck;
        gemm_body32<0>(A, W, bias, C, nullptr, mBase, nBase, As0, Bs0, As1, Bs1);
    }
}

// ---------------------------------------------------------------------------
// 2b) gemm_out (unchanged from round 10 — verified win): BM=64 x BN=128,
//     512 blocks = 2 blocks/CU, BK=64 single-buffer.
// ---------------------------------------------------------------------------
__global__ __launch_bounds__(256) void gemm_out_kernel(
    const u16* __restrict__ A, const u16* __restrict__ W,
    const float* __restrict__ bias, float* __restrict__ Cf)
{
    constexpr int K = 1024, N = 1024;
    __shared__ __align__(16) u16 As[64 * 64];     //  8 KB
    __shared__ __align__(16) u16 Bs[128 * 64];    // 16 KB
    const int tid = threadIdx.x;
    const int wv = tid >> 6, ln = tid & 63, l15 = ln & 15, quad = ln >> 4;
    const int wn = wv * 32;

    // 512 blocks (8 x, 64 y), XCD swizzle chunk = 64
    const int lin = blockIdx.x + 8 * blockIdx.y;                      // 0..511
    const int sw  = (lin & 7) * 64 + (lin >> 3);
    const int x = sw & 7, y = sw >> 3;
    const int mBase = y * 64, nBase = x * 128;

    // A staging: 64x64 u16 = 512 16B-units, 2 rounds; B: 128x64 = 4 rounds
    const u16* Aptr[2]; const u16* Wptr[4];
    #pragma unroll
    for (int r = 0; r < 2; ++r) {
        int p = r * 256 + wv * 64 + ln;     // 0..511
        int row = p >> 3;                   // 0..63
        int c = (p & 7) ^ (row & 7);
        Aptr[r] = A + (size_t)(mBase + row) * K + c * 8;
    }
    #pragma unroll
    for (int r = 0; r < 4; ++r) {
        int p = r * 256 + wv * 64 + ln;     // 0..1023
        int row = p >> 3;                   // 0..127
        int c = (p & 7) ^ (row & 7);
        Wptr[r] = W + (size_t)(nBase + row) * K + c * 8;
    }

    floatx4 acc[4][2] = {};

    for (int k0 = 0; k0 < K; k0 += 64) {
        __syncthreads();
        #pragma unroll
        for (int r = 0; r < 2; ++r)
            load16_lds(Aptr[r] + k0, &As[(r * 256 + wv * 64) * 8]);
        #pragma unroll
        for (int r = 0; r < 4; ++r)
            load16_lds(Wptr[r] + k0, &Bs[(r * 256 + wv * 64) * 8]);
        __syncthreads();
        #pragma unroll
        for (int t = 0; t < 2; ++t) {
            bf16x8 af[4], bfr[2];
            #pragma unroll
            for (int i = 0; i < 4; ++i)
                af[i] = *(const bf16x8*)&As[swz64(i * 16 + l15, t * 4 + quad)];
            #pragma unroll
            for (int j = 0; j < 2; ++j)
                bfr[j] = *(const bf16x8*)&Bs[swz64(wn + j * 16 + l15, t * 4 + quad)];
            #pragma unroll
            for (int i = 0; i < 4; ++i)
                #pragma unroll
                for (int j = 0; j < 2; ++j)
                    acc[i][j] = __builtin_amdgcn_mfma_f32_16x16x32_bf16(af[i], bfr[j], acc[i][j], 0, 0, 0);
        }
    }

    #pragma unroll
    for (int i = 0; i < 4; ++i) {
        #pragma unroll
        for (int j = 0; j < 2; ++j) {
            int col = nBase + wn + j * 16 + l15;
            float bcol = bias[col];
            #pragma unroll
            for (int r = 0; r < 4; ++r) {
                int row = mBase + i * 16 + quad * 4 + r;
                Cf[(size_t)row * N + col] = acc[i][j][r] + bcol;
            }
        }
    }
}

// ---------------------------------------------------------------------------
// 3) Flash attention (unchanged from round 5): single-buffer K/V staging +
//    XCD swizzle + fragment-order bias + operand-swapped PV.
// ---------------------------------------------------------------------------
__global__ __launch_bounds__(256) void attn_kernel(
    const u16* __restrict__ Qf, const u16* __restrict__ Kf,
    const u16* __restrict__ Vt, const u16* __restrict__ biasT,
    u16* __restrict__ Attn)
{
    __shared__ __align__(16) u16 Qs[64 * 64];
    __shared__ __align__(16) u16 Ks[64 * 64];
    __shared__ __align__(16) u16 Vs[64 * 64];      // [dk][ks] swizzled
    __shared__ __align__(16) u16 Ps[4][16 * 72];   // per-wave [q][k], +8 pad
    const int tid = threadIdx.x;
    const int wv = tid >> 6, ln = tid & 63, l15 = ln & 15, quad = ln >> 4;

    // T1: bijective XCD swizzle (1024 blocks, 1024%8==0).
    const int lin = blockIdx.x + 16 * blockIdx.y + 256 * blockIdx.z;  // 0..1023
    const int sw  = (lin & 7) * 128 + (lin >> 3);
    const int qt = sw & 15, h = (sw >> 4) & 15, b = sw >> 8;
    const int q0 = qt * 64;

    // 64x64-u16 staging map (8 chunks/row)
    int row64[2], col64[2];
    #pragma unroll
    for (int r = 0; r < 2; ++r) {
        int p = r * 256 + wv * 64 + ln;
        row64[r] = p >> 3;
        col64[r] = ((p & 7) ^ (row64[r] & 7)) * 8;
    }

    // stage Q tile [64 q][64 dk]
    #pragma unroll
    for (int r = 0; r < 2; ++r)
        load16_lds(Qf + ((size_t)(b * SS + q0 + row64[r])) * DD + h * DKK + col64[r],
                   &Qs[(r * 256 + wv * 64) * 8]);
    __syncthreads();

    // loop-invariant Q fragments (B-operand in QK^T)
    bf16x8 aq[2];
    #pragma unroll
    for (int t = 0; t < 2; ++t)
        aq[t] = *(const bf16x8*)&Qs[swz64(wv * 16 + l15, t * 4 + quad)];

    const size_t vt_head = ((size_t)(b * HH + h)) * DKK * SS;
    const u16* Kp[2]; const u16* Vp[2];
    #pragma unroll
    for (int r = 0; r < 2; ++r) {
        Kp[r] = Kf + ((size_t)(b * SS + row64[r])) * DD + h * DKK + col64[r];
        Vp[r] = Vt + vt_head + (size_t)row64[r] * SS + col64[r];
    }

    // bias: fragment-order layout [b][kt][j][quad][q][4]; per-lane base
    const int qq = q0 + wv * 16 + l15;
    const u16* bpT = biasT + (size_t)b * 1048576 + (size_t)quad * 4096 + (size_t)qq * 4;

    floatx4 o[4] = {};
    float rsum = 0.f;

    for (int kt = 0; kt < 16; ++kt) {
        const int kk0 = kt * 64;
        __syncthreads();    // prior-iteration K/V LDS reads complete
        #pragma unroll
        for (int r = 0; r < 2; ++r) {
            load16_lds(Kp[r] + (size_t)kk0 * DD, &Ks[(r * 256 + wv * 64) * 8]);
            load16_lds(Vp[r] + kk0, &Vs[(r * 256 + wv * 64) * 8]);
        }
        __syncthreads();    // staging complete

        // bias loads: 4 coalesced uint2, latency hides under QK MFMAs
        uint2 braw[4];
        #pragma unroll
        for (int j = 0; j < 4; ++j)
            braw[j] = *(const uint2*)&bpT[(size_t)kt * 65536 + j * 16384];

        // S^T = K Q^T : row = k-within-16 (quad*4+r), col = q (l15)
        floatx4 sfr[4];
        #pragma unroll
        for (int j = 0; j < 4; ++j) {
            bf16x8 bk0 = *(const bf16x8*)&Ks[swz64(j * 16 + l15, quad)];
            bf16x8 bk1 = *(const bf16x8*)&Ks[swz64(j * 16 + l15, 4 + quad)];
            floatx4 s = {};
            s = __builtin_amdgcn_mfma_f32_16x16x32_bf16(bk0, aq[0], s, 0, 0, 0);
            sfr[j] = __builtin_amdgcn_mfma_f32_16x16x32_bf16(bk1, aq[1], s, 0, 0, 0);
        }

        // softmax: p = exp2(s*0.1803.. + bias2); packed b64 P-stores
        #pragma unroll
        for (int j = 0; j < 4; ++j) {
            float b0 = __uint_as_float(braw[j].x << 16);
            float b1 = __uint_as_float(braw[j].x & 0xffff0000u);
            float b2 = __uint_as_float(braw[j].y << 16);
            float b3 = __uint_as_float(braw[j].y & 0xffff0000u);
            float p0 = __builtin_amdgcn_exp2f(fmaf(sfr[j][0], QKSCALE, b0));
            float p1 = __builtin_amdgcn_exp2f(fmaf(sfr[j][1], QKSCALE, b1));
            float p2 = __builtin_amdgcn_exp2f(fmaf(sfr[j][2], QKSCALE, b2));
            float p3 = __builtin_amdgcn_exp2f(fmaf(sfr[j][3], QKSCALE, b3));
            rsum += (p0 + p1) + (p2 + p3);
            uint2 pk;
            pk.x = (__float_as_uint(p0) >> 16) | (__float_as_uint(p1) & 0xffff0000u);
            pk.y = (__float_as_uint(p2) >> 16) | (__float_as_uint(p3) & 0xffff0000u);
            *(uint2*)&Ps[wv][l15 * 72 + j * 16 + quad * 4] = pk;
        }

        // O^T += V^T P^T  (operand-swapped: A=V-frag, B=P-frag; Ps wave-private)
        #pragma unroll
        for (int t = 0; t < 2; ++t) {
            bf16x8 ap = *(const bf16x8*)&Ps[wv][l15 * 72 + t * 32 + quad * 8];
            #pragma unroll
            for (int j = 0; j < 4; ++j) {
                bf16x8 bvv = *(const bf16x8*)&Vs[swz64(j * 16 + l15, t * 4 + quad)];
                o[j] = __builtin_amdgcn_mfma_f32_16x16x32_bf16(bvv, ap, o[j], 0, 0, 0);
            }
        }
    }

    // rsum: butterfly over quads (bits 4,5) -> every lane holds the full
    // row-sum for its own q = l15.  No LDS bounce needed.
    rsum += __shfl_xor(rsum, 16);
    rsum += __shfl_xor(rsum, 32);
    const float ri = 1.0f / rsum;

    // epilogue: o[j][r] = O[q=qq][dk = j*16 + quad*4 + r] -> 4 ushort4 stores
    u16* outp = Attn + ((size_t)(b * SS + qq)) * DD + h * DKK + quad * 4;
    #pragma unroll
    for (int j = 0; j < 4; ++j) {
        ushort4 v4;
        v4.x = f2bf(o[j][0] * ri);
        v4.y = f2bf(o[j][1] * ri);
        v4.z = f2bf(o[j][2] * ri);
        v4.w = f2bf(o[j][3] * ri);
        *(ushort4*)&outp[j * 16] = v4;
    }
}

// ---------------------------------------------------------------------------
// launch
// ---------------------------------------------------------------------------
extern "C" void kernel_launch(void* const* d_in, const int* in_sizes, int n_in,
                              void* d_out, int out_size, void* d_ws, size_t ws_size,
                              hipStream_t stream)
{
    const float* Qx  = (const float*)d_in[0];
    const float* Kx  = (const float*)d_in[1];
    const float* Vx  = (const float*)d_in[2];
    const float* prob = (const float*)d_in[3];
    const int*   mask = (const int*)d_in[4];
    const int*   lam  = (const int*)d_in[5];
    const float* Wq  = (const float*)d_in[6];
    const float* bq  = (const float*)d_in[7];
    const float* Wk  = (const float*)d_in[8];
    const float* bk  = (const float*)d_in[9];
    const float* Wv  = (const float*)d_in[10];
    const float* bv  = (const float*)d_in[11];
    const float* Wo  = (const float*)d_in[12];
    const float* bo  = (const float*)d_in[13];

    char* ws = (char*)d_ws;
    const size_t MB = 1024 * 1024;
    u16*   Xq     = (u16*)(ws + 0 * MB);
    u16*   Xk     = (u16*)(ws + 8 * MB);
    u16*   Xv     = (u16*)(ws + 16 * MB);
    u16*   wq     = (u16*)(ws + 24 * MB);
    u16*   wk     = (u16*)(ws + 26 * MB);
    u16*   wvp    = (u16*)(ws + 28 * MB);
    u16*   wo     = (u16*)(ws + 30 * MB);
    u16*   q_flat = (u16*)(ws + 32 * MB);
    u16*   k_flat = (u16*)(ws + 40 * MB);
    u16*   vt     = (u16*)(ws + 56 * MB);
    u16*   biasT  = (u16*)(ws + 64 * MB);   // 8MB bf16 [b][kt][j][quad][q][4], prescaled by log2e
    u16*   attn   = (u16*)(ws + 80 * MB);

    float* maskOut = (out_size >= 2 * BB * SS * DD) ? (float*)d_out + (size_t)BB * SS * DD
                                                    : nullptr;

    prep_kernel<<<5120, 256, 0, stream>>>(Qx, Kx, Vx, Wq, Wk, Wv, Wo, prob, mask, lam,
                                          Xq, Xk, Xv, wq, wk, wvp, wo, biasT, maskOut);
    gemm_qkv_kernel<<<dim3(8, 32, 3), 256, 0, stream>>>(Xq, Xk, Xv, wq, wk, wvp,
                                                        bq, bk, bv, q_flat, k_flat, vt);
    attn_kernel<<<dim3(16, 16, 4), 256, 0, stream>>>(q_flat, k_flat, vt, biasT, attn);
    gemm_out_kernel<<<dim3(8, 64), 256, 0, stream>>>(attn, wo, bo, (float*)d_out);
}